// Round 6
// baseline (391.279 us; speedup 1.0000x reference)
//
#include <hip/hip_runtime.h>
#include <hip/hip_bf16.h>

// Shapes: B=64 S=32 H=40 W=64 ; conv1: 1->32 (20x32) ; conv2: 32->64 (10x16) ; conv3: 64->32 (5x8)
// SENS=1283 UNITS=48 MOTOR=4 NA=2 UNFOLDS=6

typedef __attribute__((ext_vector_type(8))) short bshort8;   // 8 bf16 (4 VGPR) MFMA frag
typedef __attribute__((ext_vector_type(4))) float f32x4;     // MFMA acc

// ---- workspace layout (float units) ----
constexpr long OFF_SEQ  = 0;                 // 2048*1283 = 2627584
constexpr long OFF_SP4  = 2627584;           // sensory params float4[1283*48] = 246336 fl
constexpr long OFF_RP4  = 2873920;           // rec COMPACT region (11584 of 12288 fl):
                                             //   [0,9216)      float4 cp4[36][64]
                                             //   [9216,11520)  int    jadr[36][64] (byte addr j*4)
                                             //   [11520,11584) int    nnz[64]
constexpr long OFF_CM   = 2886208;           // cm_t(64), gl(64), gl*vleak(64)
constexpr long OFF_W2B  = 2886400;           // conv2 bf16 frags (K-repacked): 24576 bf16 = 12288 fl
constexpr long OFF_W3B  = 2898688;           // conv3 bf16 frags: 18432 bf16 = 9216 fl
constexpr long OFF_PART = 2907904;           // float2[2048*48] = 196608 fl
// end 3104512 fl = 12.42 MB

__device__ __forceinline__ float sp_(float x) {
    return fmaxf(x, 0.f) + log1pf(expf(-fabsf(x)));   // stable softplus
}

// ---------------------------------------------------------------------------
// prep: rec section = per-u compacted nonzero list (validated in R1: compact
// build at cap 36 passed with absmax identical to dense). Other sections
// verbatim.
// ---------------------------------------------------------------------------
__global__ void prep_kernel(const float* __restrict__ sens_w, const float* __restrict__ sens_mu,
                            const float* __restrict__ sens_sigma, const float* __restrict__ sens_erev,
                            const int* __restrict__ sens_mask,
                            const float* __restrict__ rec_w, const float* __restrict__ rec_mu,
                            const float* __restrict__ rec_sigma, const float* __restrict__ rec_erev,
                            const int* __restrict__ rec_mask,
                            const float* __restrict__ gleak, const float* __restrict__ vleak,
                            const float* __restrict__ cm,
                            const float* __restrict__ w2, const float* __restrict__ w3,
                            float* __restrict__ ws) {
    const float L2E = 1.4426950408889634f;
    int i = blockIdx.x * 256 + threadIdx.x;
    if (i < 61584) {                       // sensory packed [k 1283][u 48]
        float m  = sens_mask[i] ? 1.f : 0.f;
        float sw = sp_(sens_w[i]) * m;
        float sg = sens_sigma[i], mu = sens_mu[i];
        ((float4*)(ws + OFF_SP4))[i] =
            make_float4(-sg * L2E, sg * mu * L2E, sw * sens_erev[i], sw);
    } else if (i < 64656) {                // recurrent compact build (first 64 lanes)
        int q = i - 61584;
        if (q < 64) {
            float4* cp4 = (float4*)(ws + OFF_RP4);
            int* jadr = (int*)(ws + OFF_RP4 + 9216);
            int* nz   = (int*)(ws + OFF_RP4 + 11520);
            int cnt = 0;
            if (q < 48) {
                for (int j = 0; j < 48; ++j) {
                    int idx = j * 48 + q;
                    if (rec_mask[idx] && cnt < 36) {
                        float sw = sp_(rec_w[idx]);
                        float sg = rec_sigma[idx], mu = rec_mu[idx];
                        cp4[cnt * 64 + q] = make_float4(-sg * L2E, sg * mu * L2E,
                                                        sw * rec_erev[idx], sw);
                        jadr[cnt * 64 + q] = j * 4;
                        ++cnt;
                    }
                }
            }
            nz[q] = cnt;
            for (int e = cnt; e < 36; ++e) {   // padded entries contribute exactly 0
                cp4[e * 64 + q] = make_float4(0.f, 0.f, 0.f, 0.f);
                jadr[e * 64 + q] = 0;
            }
        }
    } else if (i < 64704) {
        int u = i - 64656;                 // u < 48
        float g = sp_(gleak[u]);
        ws[OFF_CM + u]       = sp_(cm[u]) * 6.f;
        ws[OFF_CM + 64 + u]  = g;
        ws[OFF_CM + 128 + u] = g * vleak[u];
    } else if (i < 89280) {                // w2b K-repacked frags (24576)
        int n = i - 64704;
        int j = n & 7, l = (n >> 3) & 63, t2 = n >> 9;   // t2 0..47
        int wv = t2 & 3;
        int r  = t2 >> 2;                  // 0..11 = (h*3+ky)*2+xp
        int xp = r & 1, hk = r >> 1;       // hk = h*3+ky
        int ky = hk % 3, h = hk / 3;
        int oc = wv * 16 + (l & 15);
        int kgB = l >> 4;
        int icl = (kgB & 1) * 8 + j;
        int ic = h * 16 + icl;
        int kx = 2 * xp + (kgB >> 1);
        float val = (kx == 3) ? 0.f : w2[((oc * 32 + ic) * 3 + ky) * 3 + kx];
        ((__hip_bfloat16*)(ws + OFF_W2B))[n] = __float2bfloat16(val);
    } else if (i < 107712) {               // w3b frags (unchanged mapping)
        int n = i - 89280;
        int j = n & 7, l = (n >> 3) & 63, t3 = n >> 9;
        int h = t3 & 1, u2 = t3 >> 1;
        int nt = u2 / 9, p = u2 % 9;
        int ky = p / 3, kx = p % 3;
        int oc = nt * 16 + (l & 15);
        int ic = h * 32 + (l >> 4) * 8 + j;
        ((__hip_bfloat16*)(ws + OFF_W3B))[n] =
            __float2bfloat16(w3[((oc * 64 + ic) * 3 + ky) * 3 + kx]);
    }
}

// ---------------------------------------------------------------------------
// Fused CNN (verbatim from the 294.7us best).
// ---------------------------------------------------------------------------
#define IMGB 0
#define C1H  5424
#define A2E  0
#define A2O  12672
#define SMB  28272

__global__ __launch_bounds__(256, 4) void cnn_kernel(
    const float* __restrict__ depth, const float* __restrict__ relpos,
    const float* __restrict__ w1, const float* __restrict__ b1,
    const float* __restrict__ b2, const float* __restrict__ b3,
    const __hip_bfloat16* __restrict__ w2b, const __hip_bfloat16* __restrict__ w3b,
    float* __restrict__ seq) {
    __shared__ __align__(16) char smraw[SMB];
    const int t = threadIdx.x;
    const int img = blockIdx.x;
    const int l = t & 63;
    const int wvu = __builtin_amdgcn_readfirstlane(t >> 6);
    const int m = l & 15, kg = l >> 4;

    for (int i = t; i < 7068; i += 256) ((uint*)smraw)[i] = 0u;
    __syncthreads();
    for (int i = t; i < 1280; i += 256) {
        int pos = 2 * i;
        int h = pos >> 6, w = pos & 63;
        float2 d = *(const float2*)(depth + (long)img * 2560 + pos);
        __hip_bfloat162 pk = __float22bfloat162_rn(d);
        *(__hip_bfloat162*)(smraw + IMGB + ((h + 1) * 66 + (w + 2)) * 2) = pk;
    }
    __syncthreads();

    const __hip_bfloat16* imgp = (const __hip_bfloat16*)(smraw + IMGB);
    f32x4 acc[10];
    {
        float bias = b2[wvu * 16 + m];
#pragma unroll
        for (int mt = 0; mt < 10; ++mt) acc[mt] = (f32x4){bias, bias, bias, bias};
    }

#pragma unroll 1
    for (int h = 0; h < 2; ++h) {
        const int ocb = h * 16 + wvu * 4;      // uniform
        float wv4[4][9], bv4[4];
#pragma unroll
        for (int j = 0; j < 4; ++j) {
            bv4[j] = b1[ocb + j];
#pragma unroll
            for (int k = 0; k < 9; ++k) wv4[j][k] = w1[(ocb + j) * 9 + k];
        }
#pragma unroll 1
        for (int i = 0; i < 10; ++i) {
            int p = l + (i << 6);
            int y1 = p >> 5, x1 = p & 31;
            float xin[9];
#pragma unroll
            for (int ky = 0; ky < 3; ++ky)
#pragma unroll
                for (int kx = 0; kx < 3; ++kx)
                    xin[ky * 3 + kx] = __bfloat162float(imgp[(2 * y1 + ky) * 66 + 2 * x1 + kx + 1]);
            float o[4];
#pragma unroll
            for (int j = 0; j < 4; ++j) {
                float a = bv4[j];
#pragma unroll
                for (int k = 0; k < 9; ++k) a = fmaf(wv4[j][k], xin[k], a);
                o[j] = fmaxf(a, 0.f);
            }
            char* cb = smraw + C1H + (((y1 + 1) * 34) + (x1 + 1)) * 32 + wvu * 8;
            *(__hip_bfloat162*)cb       = __float22bfloat162_rn(make_float2(o[0], o[1]));
            *(__hip_bfloat162*)(cb + 4) = __float22bfloat162_rn(make_float2(o[2], o[3]));
        }
        bshort8 Bh[6];
#pragma unroll
        for (int f = 0; f < 6; ++f)
            Bh[f] = *(const bshort8*)(w2b + (((h * 6 + f) * 4 + wvu) * 64 + l) * 8);
        __syncthreads();   // c1h pass-h ready
#pragma unroll
        for (int ky = 0; ky < 3; ++ky) {
#pragma unroll
            for (int xp = 0; xp < 2; ++xp) {
                bshort8 Bp = Bh[ky * 2 + xp];
                const char* base = smraw + C1H + (ky * 34 + 2 * m + 2 * xp + (kg >> 1)) * 32 + (kg & 1) * 16;
#pragma unroll
                for (int mt = 0; mt < 10; ++mt) {
                    bshort8 A = *(const bshort8*)(base + mt * 2176);   // 2 rows * 34 cols * 32 B
                    acc[mt] = __builtin_amdgcn_mfma_f32_16x16x32_bf16(A, Bp, acc[mt], 0, 0, 0);
                }
            }
        }
        __syncthreads();   // reads done before next conv1 overwrite / a2 overlay
    }

    for (int i = t; i < 6336; i += 256) ((uint*)smraw)[i] = 0u;
    __syncthreads();
    {
        int oc = wvu * 16 + m;
        int q = oc >> 3, sub = oc & 7;
#pragma unroll
        for (int mt = 0; mt < 10; ++mt) {
            int row = mt + 1;
#pragma unroll
            for (int reg = 0; reg < 4; ++reg) {
                int x2 = kg * 4 + reg;
                int odd = x2 & 1;
                int xi = odd ? ((x2 + 1) >> 1) : (x2 >> 1);
                char* ab = smraw + (odd ? A2O : A2E);
                float v = fmaxf(acc[mt][reg], 0.f);
                *(__hip_bfloat16*)(ab + (((q * 11 + row) * 9 + xi) * 8 + sub) * 2) = __float2bfloat16(v);
            }
        }
    }
    __syncthreads();

    {
        const int nt = wvu & 1;
        const bool two = wvu < 2;
        f32x4 c3a = (f32x4){0.f, 0.f, 0.f, 0.f};
        f32x4 c3b = (f32x4){0.f, 0.f, 0.f, 0.f};
        const int xb = m & 7, yb = m >> 3;
#pragma unroll
        for (int p = 0; p < 9; ++p) {
            int ky = p / 3, kx = p % 3;
            const char* arr = smraw + ((kx == 1) ? A2E : A2O);
            int xi3 = xb + (kx == 2);
#pragma unroll
            for (int h = 0; h < 2; ++h) {
                bshort8 B = *(const bshort8*)(w3b + (((nt * 9 + p) * 2 + h) * 64 + l) * 8);
                int q = h * 4 + kg;
                const char* base = arr + ((q * 11 + 2 * yb + ky) * 9 + xi3) * 16;
                if (two) {
                    bshort8 A0 = *(const bshort8*)(base);
                    c3a = __builtin_amdgcn_mfma_f32_16x16x32_bf16(A0, B, c3a, 0, 0, 0);
                    bshort8 A2 = *(const bshort8*)(base + 1152);
                    c3b = __builtin_amdgcn_mfma_f32_16x16x32_bf16(A2, B, c3b, 0, 0, 0);
                } else {
                    bshort8 A1 = *(const bshort8*)(base + 576);
                    c3a = __builtin_amdgcn_mfma_f32_16x16x32_bf16(A1, B, c3a, 0, 0, 0);
                }
            }
        }
        __syncthreads();
        float* sb = (float*)smraw;
        int oc = nt * 16 + m;
        float bv = b3[oc];
        int ob40 = oc * 40;
        if (two) {
#pragma unroll
            for (int reg = 0; reg < 4; ++reg) {
                sb[ob40 + kg * 4 + reg] = fmaxf(c3a[reg] + bv, 0.f);
                int px2 = 32 + kg * 4 + reg;
                if (px2 < 40) sb[ob40 + px2] = fmaxf(c3b[reg] + bv, 0.f);
            }
        } else {
#pragma unroll
            for (int reg = 0; reg < 4; ++reg)
                sb[ob40 + 16 + kg * 4 + reg] = fmaxf(c3a[reg] + bv, 0.f);
        }
        __syncthreads();
        for (int i = t; i < 1283; i += 256)
            seq[(long)img * 1283 + i] = (i < 1280) ? sb[i] : relpos[img * 3 + (i - 1280)];
    }
}

// ---------------------------------------------------------------------------
// Sensory (verbatim): pair-blocked, 256 blocks x 768 thr, 48KB LDS.
// ---------------------------------------------------------------------------
__global__ __launch_bounds__(768) void sensory_kernel(
    const float* __restrict__ sp, const float* __restrict__ seq,
    const float* __restrict__ iw, const float* __restrict__ ibias,
    float2* __restrict__ part) {
    const float4* P4 = (const float4*)sp;
    __shared__ __align__(16) char sbuf[49152];
    float*  IT  = (float*)sbuf;
    float2* red = (float2*)sbuf;
    const int t = threadIdx.x;
    const int pb = blockIdx.x * 8;

    for (int p = 0; p < 8; ++p)
        for (int k = t; k < 1283; k += 768)
            IT[k * 8 + p] = fmaf(seq[(long)(pb + p) * 1283 + k], iw[k], ibias[k]);
    __syncthreads();

    const int u = t % 48, kg = t / 48;
    float2 acc[8];
#pragma unroll
    for (int p = 0; p < 8; ++p) acc[p] = make_float2(0.f, 0.f);

#pragma unroll 2
    for (int i = 0; i < 81; ++i) {
        int k = kg + 16 * i;
        if (k < 1283) {
            float4 pv = P4[k * 48 + u];
            float4 Ia = *(const float4*)&IT[k * 8];
            float4 Ib = *(const float4*)&IT[k * 8 + 4];
            float r0 = __builtin_amdgcn_rcpf(1.f + __builtin_amdgcn_exp2f(fmaf(pv.x, Ia.x, pv.y)));
            float r1 = __builtin_amdgcn_rcpf(1.f + __builtin_amdgcn_exp2f(fmaf(pv.x, Ia.y, pv.y)));
            float r2 = __builtin_amdgcn_rcpf(1.f + __builtin_amdgcn_exp2f(fmaf(pv.x, Ia.z, pv.y)));
            float r3 = __builtin_amdgcn_rcpf(1.f + __builtin_amdgcn_exp2f(fmaf(pv.x, Ia.w, pv.y)));
            float r4 = __builtin_amdgcn_rcpf(1.f + __builtin_amdgcn_exp2f(fmaf(pv.x, Ib.x, pv.y)));
            float r5 = __builtin_amdgcn_rcpf(1.f + __builtin_amdgcn_exp2f(fmaf(pv.x, Ib.y, pv.y)));
            float r6 = __builtin_amdgcn_rcpf(1.f + __builtin_amdgcn_exp2f(fmaf(pv.x, Ib.z, pv.y)));
            float r7 = __builtin_amdgcn_rcpf(1.f + __builtin_amdgcn_exp2f(fmaf(pv.x, Ib.w, pv.y)));
            acc[0].x = fmaf(pv.z, r0, acc[0].x); acc[0].y = fmaf(pv.w, r0, acc[0].y);
            acc[1].x = fmaf(pv.z, r1, acc[1].x); acc[1].y = fmaf(pv.w, r1, acc[1].y);
            acc[2].x = fmaf(pv.z, r2, acc[2].x); acc[2].y = fmaf(pv.w, r2, acc[2].y);
            acc[3].x = fmaf(pv.z, r3, acc[3].x); acc[3].y = fmaf(pv.w, r3, acc[3].y);
            acc[4].x = fmaf(pv.z, r4, acc[4].x); acc[4].y = fmaf(pv.w, r4, acc[4].y);
            acc[5].x = fmaf(pv.z, r5, acc[5].x); acc[5].y = fmaf(pv.w, r5, acc[5].y);
            acc[6].x = fmaf(pv.z, r6, acc[6].x); acc[6].y = fmaf(pv.w, r6, acc[6].y);
            acc[7].x = fmaf(pv.z, r7, acc[7].x); acc[7].y = fmaf(pv.w, r7, acc[7].y);
        }
    }
    __syncthreads();
#pragma unroll
    for (int p = 0; p < 8; ++p) red[(kg * 8 + p) * 48 + u] = acc[p];
    __syncthreads();
    if (t < 384) {
        int p = t / 48, uu = t - p * 48;
        float sn = 0.f, sd = 0.f;
#pragma unroll
        for (int g = 0; g < 16; ++g) {
            float2 rr = red[(g * 8 + p) * 48 + uu];
            sn += rr.x; sd += rr.y;
        }
        part[(long)(pb + p) * 48 + uu] = make_float2(sn, sd);
    }
}

// ---------------------------------------------------------------------------
// Recurrent v7: ONE WAVE per batch (64 blocks x 64 thr), BARRIER-FREE.
// R5 decomposition: serial ~40us (barrier + ds_write/read round trip per
// unfold) + parallel ~27us (dense trans). This kills both:
//  - lane = u, vn lives in the wave; v[j] gather = in-wave ds_bpermute
//    (no barrier, no LDS exchange, no __syncthreads in the 192-unfold chain)
//  - j-loop over prep-compacted nonzeros (~30% density; compaction + rcp-
//    Newton already validated end-to-end in R1 with identical absmax)
// Params as 4 scalar float arrays (NOT float4 components — v6's asm on
// vector components likely demoted P to scratch, VGPR stuck at 40) with
// static unrolled indexing + scalar keep-alive.
// Falsifier: VGPR_Count must be >=200; if ~40 again -> params-in-LDS next.
// ---------------------------------------------------------------------------
__global__ __launch_bounds__(64, 1) void recurrent_kernel(
    const float* __restrict__ rp, const float* __restrict__ cmglv,
    const float2* __restrict__ part,
    const float* __restrict__ out_w, const float* __restrict__ out_b,
    const float* __restrict__ head_w, const float* __restrict__ head_b,
    float* __restrict__ outp) {
    __shared__ float2 WL[1536];        // sensory partials for this batch (12 KB)
    const int t = threadIdx.x;         // lane; u = t for t<48
    const int b = blockIdx.x;
    const bool uval = t < 48;
    const int u = uval ? t : 47;       // idle lanes mirror u=47 (results discarded)

    // ---- compact params -> registers (scalar arrays, static indices) ----
    const float4* CP4 = (const float4*)rp;
    const int* JAD = (const int*)(rp + 9216);
    const int* NNZ = (const int*)(rp + 11520);
    float px[36], py[36], pz[36], pw[36];
    int adr[36];
#pragma unroll
    for (int e = 0; e < 36; ++e) {
        float4 q = CP4[e * 64 + t];    // [36][64], u>=48 rows zero-padded by prep
        px[e] = q.x; py[e] = q.y; pz[e] = q.z; pw[e] = q.w;
        adr[e] = JAD[e * 64 + t];
    }
#pragma unroll
    for (int e = 0; e < 36; ++e) {
        asm volatile("" : "+v"(px[e]), "+v"(py[e]), "+v"(pz[e]), "+v"(pw[e]));
        asm volatile("" : "+v"(adr[e]));
    }

    // uniform chunk bound: wave-max nnz (padded entries contribute exactly 0)
    int NJ = uval ? NNZ[t] : 0;
#pragma unroll
    for (int off = 32; off; off >>= 1) NJ = max(NJ, __shfl_xor(NJ, off, 64));
    NJ = __builtin_amdgcn_readfirstlane(NJ);

    // stage sensory partials
    for (int i = t; i < 1536; i += 64) WL[i] = part[(long)b * 1536 + i];

    const float cmt = uval ? cmglv[u] : 0.f;
    const float gl  = uval ? cmglv[64 + u] : 0.f;
    const float glv = uval ? cmglv[128 + u] : 0.f;
    const float cg  = cmt + gl + 1e-8f;
    float ow = 0.f, ob = 0.f;
    if (t < 4) { ow = out_w[t]; ob = out_b[t]; }
    __syncthreads();   // once: WL staging visible (outside the serial chain)

    float vn = 0.f, yacc = 0.f;
#pragma unroll 1
    for (int s = 0; s < 32; ++s) {
        float2 wnd = uval ? WL[s * 48 + u] : make_float2(0.f, 0.f);
        const float basen = glv + wnd.x;
        const float based = cg + wnd.y;
#pragma unroll 1
        for (int unf = 0; unf < 6; ++unf) {
            // gather pass: all bpermutes issued up-front (latency overlapped)
            int vv[36];
            const int vni = __float_as_int(vn);
#pragma unroll
            for (int c = 0; c < 6; ++c) {
                if (c * 6 < NJ) {
#pragma unroll
                    for (int k = 0; k < 6; ++k)
                        vv[c * 6 + k] = __builtin_amdgcn_ds_bpermute(adr[c * 6 + k], vni);
                }
            }
            // compute pass: dual accumulator chains
            float pn0 = 0.f, pd0 = 0.f, pn1 = 0.f, pd1 = 0.f;
#pragma unroll
            for (int c = 0; c < 6; ++c) {
                if (c * 6 < NJ) {
#pragma unroll
                    for (int k = 0; k < 6; ++k) {
                        int e = c * 6 + k;
                        float vj = __int_as_float(vv[e]);
                        float rr = __builtin_amdgcn_rcpf(
                            1.f + __builtin_amdgcn_exp2f(fmaf(px[e], vj, py[e])));
                        if (k & 1) { pn1 = fmaf(pz[e], rr, pn1); pd1 = fmaf(pw[e], rr, pd1); }
                        else       { pn0 = fmaf(pz[e], rr, pn0); pd0 = fmaf(pw[e], rr, pd0); }
                    }
                }
            }
            float num = fmaf(cmt, vn, basen) + (pn0 + pn1);
            float den = based + (pd0 + pd1);
            float r0 = __builtin_amdgcn_rcpf(den);
            r0 = r0 * fmaf(-den, r0, 2.f);       // 1 Newton step: ~1 ulp
            vn = num * r0;
        }
        if (t < 4) yacc = fmaf(vn, ow, yacc) + ob;
    }
    float y0 = __shfl(yacc, 0, 64), y1 = __shfl(yacc, 1, 64);
    float y2 = __shfl(yacc, 2, 64), y3 = __shfl(yacc, 3, 64);
    if (t < 2) {
        const float inv = 1.f / 32.f;
        float o = fmaf(y0 * inv, head_w[t],
                  fmaf(y1 * inv, head_w[2 + t],
                  fmaf(y2 * inv, head_w[4 + t],
                  fmaf(y3 * inv, head_w[6 + t], head_b[t]))));
        outp[b * 2 + t] = tanhf(o);
    }
}

extern "C" void kernel_launch(void* const* d_in, const int* in_sizes, int n_in,
                              void* d_out, int out_size, void* d_ws, size_t ws_size,
                              hipStream_t stream) {
    const float* depth      = (const float*)d_in[0];
    const float* relpos     = (const float*)d_in[1];
    const float* w1         = (const float*)d_in[2];
    const float* b1         = (const float*)d_in[3];
    const float* w2         = (const float*)d_in[4];
    const float* b2         = (const float*)d_in[5];
    const float* w3         = (const float*)d_in[6];
    const float* b3         = (const float*)d_in[7];
    const float* iw         = (const float*)d_in[8];
    const float* ibias      = (const float*)d_in[9];
    const float* sens_w     = (const float*)d_in[10];
    const float* sens_mu    = (const float*)d_in[11];
    const float* sens_sigma = (const float*)d_in[12];
    const float* sens_erev  = (const float*)d_in[13];
    const float* rec_w      = (const float*)d_in[14];
    const float* rec_mu     = (const float*)d_in[15];
    const float* rec_sigma  = (const float*)d_in[16];
    const float* rec_erev   = (const float*)d_in[17];
    const float* gleak      = (const float*)d_in[18];
    const float* vleak      = (const float*)d_in[19];
    const float* cm         = (const float*)d_in[20];
    const float* out_w      = (const float*)d_in[21];
    const float* out_b      = (const float*)d_in[22];
    const float* head_w     = (const float*)d_in[23];
    const float* head_b     = (const float*)d_in[24];
    const int*   sens_mask  = (const int*)d_in[25];
    const int*   rec_mask   = (const int*)d_in[26];

    float* ws  = (float*)d_ws;
    float* out = (float*)d_out;

    prep_kernel<<<477, 256, 0, stream>>>(sens_w, sens_mu, sens_sigma, sens_erev, sens_mask,
                                         rec_w, rec_mu, rec_sigma, rec_erev, rec_mask,
                                         gleak, vleak, cm, w2, w3, ws);
    cnn_kernel<<<2048, 256, 0, stream>>>(depth, relpos, w1, b1, b2, b3,
                                         (const __hip_bfloat16*)(ws + OFF_W2B),
                                         (const __hip_bfloat16*)(ws + OFF_W3B),
                                         ws + OFF_SEQ);
    sensory_kernel<<<256, 768, 0, stream>>>(ws + OFF_SP4, ws + OFF_SEQ, iw, ibias,
                                            (float2*)(ws + OFF_PART));
    recurrent_kernel<<<64, 64, 0, stream>>>(ws + OFF_RP4, ws + OFF_CM,
                                            (const float2*)(ws + OFF_PART),
                                            out_w, out_b, head_w, head_b, out);
}

// Round 9
// 311.104 us; speedup vs baseline: 1.2577x; 1.2577x over previous
//
#include <hip/hip_runtime.h>
#include <hip/hip_bf16.h>

// Shapes: B=64 S=32 H=40 W=64 ; conv1: 1->32 (20x32) ; conv2: 32->64 (10x16) ; conv3: 64->32 (5x8)
// SENS=1283 UNITS=48 MOTOR=4 NA=2 UNFOLDS=6

typedef __attribute__((ext_vector_type(8))) short bshort8;   // 8 bf16 (4 VGPR) MFMA frag
typedef __attribute__((ext_vector_type(4))) float f32x4;     // MFMA acc

// ---- workspace layout (float units) ----
constexpr long OFF_SEQ  = 0;                 // 2048*1283 = 2627584
constexpr long OFF_SP4  = 2627584;           // sensory params float4[1283*48] = 246336 fl
constexpr long OFF_RP4  = 2873920;           // rec params float4[48 j][64 u-padded] = 12288 fl
constexpr long OFF_CM   = 2886208;           // cm_t(64), gl(64), gl*vleak(64)
constexpr long OFF_W2B  = 2886400;           // conv2 bf16 frags (K-repacked): 24576 bf16 = 12288 fl
constexpr long OFF_W3B  = 2898688;           // conv3 bf16 frags: 18432 bf16 = 9216 fl
constexpr long OFF_PART = 2907904;           // float2[2048*48] = 196608 fl
// end 3104512 fl = 12.42 MB

__device__ __forceinline__ float sp_(float x) {
    return fmaxf(x, 0.f) + log1pf(expf(-fabsf(x)));   // stable softplus
}

// quad-lane XOR reduce helpers via DPP quad_perm (VALU-speed, no LDS pipe).
__device__ __forceinline__ float qxor1_(float x) {
    return __int_as_float(__builtin_amdgcn_mov_dpp(__float_as_int(x), 0xB1, 0xF, 0xF, true));
}
__device__ __forceinline__ float qxor2_(float x) {
    return __int_as_float(__builtin_amdgcn_mov_dpp(__float_as_int(x), 0x4E, 0xF, 0xF, true));
}

// ---------------------------------------------------------------------------
// prep (dense [j 48][u 64] recurrent layout — the proven v6 version).
// ---------------------------------------------------------------------------
__global__ void prep_kernel(const float* __restrict__ sens_w, const float* __restrict__ sens_mu,
                            const float* __restrict__ sens_sigma, const float* __restrict__ sens_erev,
                            const int* __restrict__ sens_mask,
                            const float* __restrict__ rec_w, const float* __restrict__ rec_mu,
                            const float* __restrict__ rec_sigma, const float* __restrict__ rec_erev,
                            const int* __restrict__ rec_mask,
                            const float* __restrict__ gleak, const float* __restrict__ vleak,
                            const float* __restrict__ cm,
                            const float* __restrict__ w2, const float* __restrict__ w3,
                            float* __restrict__ ws) {
    const float L2E = 1.4426950408889634f;
    int i = blockIdx.x * 256 + threadIdx.x;
    if (i < 61584) {                       // sensory packed [k 1283][u 48]
        float m  = sens_mask[i] ? 1.f : 0.f;
        float sw = sp_(sens_w[i]) * m;
        float sg = sens_sigma[i], mu = sens_mu[i];
        ((float4*)(ws + OFF_SP4))[i] =
            make_float4(-sg * L2E, sg * mu * L2E, sw * sens_erev[i], sw);
    } else if (i < 64656) {                // recurrent: [j 48][u 64 padded]
        int q = i - 61584;
        int j = q >> 6, u = q & 63;
        float4 v = make_float4(0.f, 0.f, 0.f, 0.f);
        if (u < 48) {
            int idx = j * 48 + u;
            float m  = rec_mask[idx] ? 1.f : 0.f;
            float sw = sp_(rec_w[idx]) * m;
            float sg = rec_sigma[idx], mu = rec_mu[idx];
            v = make_float4(-sg * L2E, sg * mu * L2E, sw * rec_erev[idx], sw);
        }
        ((float4*)(ws + OFF_RP4))[q] = v;
    } else if (i < 64704) {
        int u = i - 64656;                 // u < 48
        float g = sp_(gleak[u]);
        ws[OFF_CM + u]       = sp_(cm[u]) * 6.f;
        ws[OFF_CM + 64 + u]  = g;
        ws[OFF_CM + 128 + u] = g * vleak[u];
    } else if (i < 89280) {                // w2b K-repacked frags (24576)
        int n = i - 64704;
        int j = n & 7, l = (n >> 3) & 63, t2 = n >> 9;   // t2 0..47
        int wv = t2 & 3;
        int r  = t2 >> 2;                  // 0..11 = (h*3+ky)*2+xp
        int xp = r & 1, hk = r >> 1;       // hk = h*3+ky
        int ky = hk % 3, h = hk / 3;
        int oc = wv * 16 + (l & 15);
        int kgB = l >> 4;
        int icl = (kgB & 1) * 8 + j;
        int ic = h * 16 + icl;
        int kx = 2 * xp + (kgB >> 1);
        float val = (kx == 3) ? 0.f : w2[((oc * 32 + ic) * 3 + ky) * 3 + kx];
        ((__hip_bfloat16*)(ws + OFF_W2B))[n] = __float2bfloat16(val);
    } else if (i < 107712) {               // w3b frags (unchanged mapping)
        int n = i - 89280;
        int j = n & 7, l = (n >> 3) & 63, t3 = n >> 9;
        int h = t3 & 1, u2 = t3 >> 1;
        int nt = u2 / 9, p = u2 % 9;
        int ky = p / 3, kx = p % 3;
        int oc = nt * 16 + (l & 15);
        int ic = h * 32 + (l >> 4) * 8 + j;
        ((__hip_bfloat16*)(ws + OFF_W3B))[n] =
            __float2bfloat16(w3[((oc * 64 + ic) * 3 + ky) * 3 + kx]);
    }
}

// ---------------------------------------------------------------------------
// Fused CNN (verbatim from the 294.7us best).
// ---------------------------------------------------------------------------
#define IMGB 0
#define C1H  5424
#define A2E  0
#define A2O  12672
#define SMB  28272

__global__ __launch_bounds__(256, 4) void cnn_kernel(
    const float* __restrict__ depth, const float* __restrict__ relpos,
    const float* __restrict__ w1, const float* __restrict__ b1,
    const float* __restrict__ b2, const float* __restrict__ b3,
    const __hip_bfloat16* __restrict__ w2b, const __hip_bfloat16* __restrict__ w3b,
    float* __restrict__ seq) {
    __shared__ __align__(16) char smraw[SMB];
    const int t = threadIdx.x;
    const int img = blockIdx.x;
    const int l = t & 63;
    const int wvu = __builtin_amdgcn_readfirstlane(t >> 6);
    const int m = l & 15, kg = l >> 4;

    for (int i = t; i < 7068; i += 256) ((uint*)smraw)[i] = 0u;
    __syncthreads();
    for (int i = t; i < 1280; i += 256) {
        int pos = 2 * i;
        int h = pos >> 6, w = pos & 63;
        float2 d = *(const float2*)(depth + (long)img * 2560 + pos);
        __hip_bfloat162 pk = __float22bfloat162_rn(d);
        *(__hip_bfloat162*)(smraw + IMGB + ((h + 1) * 66 + (w + 2)) * 2) = pk;
    }
    __syncthreads();

    const __hip_bfloat16* imgp = (const __hip_bfloat16*)(smraw + IMGB);
    f32x4 acc[10];
    {
        float bias = b2[wvu * 16 + m];
#pragma unroll
        for (int mt = 0; mt < 10; ++mt) acc[mt] = (f32x4){bias, bias, bias, bias};
    }

#pragma unroll 1
    for (int h = 0; h < 2; ++h) {
        const int ocb = h * 16 + wvu * 4;      // uniform
        float wv4[4][9], bv4[4];
#pragma unroll
        for (int j = 0; j < 4; ++j) {
            bv4[j] = b1[ocb + j];
#pragma unroll
            for (int k = 0; k < 9; ++k) wv4[j][k] = w1[(ocb + j) * 9 + k];
        }
#pragma unroll 1
        for (int i = 0; i < 10; ++i) {
            int p = l + (i << 6);
            int y1 = p >> 5, x1 = p & 31;
            float xin[9];
#pragma unroll
            for (int ky = 0; ky < 3; ++ky)
#pragma unroll
                for (int kx = 0; kx < 3; ++kx)
                    xin[ky * 3 + kx] = __bfloat162float(imgp[(2 * y1 + ky) * 66 + 2 * x1 + kx + 1]);
            float o[4];
#pragma unroll
            for (int j = 0; j < 4; ++j) {
                float a = bv4[j];
#pragma unroll
                for (int k = 0; k < 9; ++k) a = fmaf(wv4[j][k], xin[k], a);
                o[j] = fmaxf(a, 0.f);
            }
            char* cb = smraw + C1H + (((y1 + 1) * 34) + (x1 + 1)) * 32 + wvu * 8;
            *(__hip_bfloat162*)cb       = __float22bfloat162_rn(make_float2(o[0], o[1]));
            *(__hip_bfloat162*)(cb + 4) = __float22bfloat162_rn(make_float2(o[2], o[3]));
        }
        bshort8 Bh[6];
#pragma unroll
        for (int f = 0; f < 6; ++f)
            Bh[f] = *(const bshort8*)(w2b + (((h * 6 + f) * 4 + wvu) * 64 + l) * 8);
        __syncthreads();   // c1h pass-h ready
#pragma unroll
        for (int ky = 0; ky < 3; ++ky) {
#pragma unroll
            for (int xp = 0; xp < 2; ++xp) {
                bshort8 Bp = Bh[ky * 2 + xp];
                const char* base = smraw + C1H + (ky * 34 + 2 * m + 2 * xp + (kg >> 1)) * 32 + (kg & 1) * 16;
#pragma unroll
                for (int mt = 0; mt < 10; ++mt) {
                    bshort8 A = *(const bshort8*)(base + mt * 2176);   // 2 rows * 34 cols * 32 B
                    acc[mt] = __builtin_amdgcn_mfma_f32_16x16x32_bf16(A, Bp, acc[mt], 0, 0, 0);
                }
            }
        }
        __syncthreads();   // reads done before next conv1 overwrite / a2 overlay
    }

    for (int i = t; i < 6336; i += 256) ((uint*)smraw)[i] = 0u;
    __syncthreads();
    {
        int oc = wvu * 16 + m;
        int q = oc >> 3, sub = oc & 7;
#pragma unroll
        for (int mt = 0; mt < 10; ++mt) {
            int row = mt + 1;
#pragma unroll
            for (int reg = 0; reg < 4; ++reg) {
                int x2 = kg * 4 + reg;
                int odd = x2 & 1;
                int xi = odd ? ((x2 + 1) >> 1) : (x2 >> 1);
                char* ab = smraw + (odd ? A2O : A2E);
                float v = fmaxf(acc[mt][reg], 0.f);
                *(__hip_bfloat16*)(ab + (((q * 11 + row) * 9 + xi) * 8 + sub) * 2) = __float2bfloat16(v);
            }
        }
    }
    __syncthreads();

    {
        const int nt = wvu & 1;
        const bool two = wvu < 2;
        f32x4 c3a = (f32x4){0.f, 0.f, 0.f, 0.f};
        f32x4 c3b = (f32x4){0.f, 0.f, 0.f, 0.f};
        const int xb = m & 7, yb = m >> 3;
#pragma unroll
        for (int p = 0; p < 9; ++p) {
            int ky = p / 3, kx = p % 3;
            const char* arr = smraw + ((kx == 1) ? A2E : A2O);
            int xi3 = xb + (kx == 2);
#pragma unroll
            for (int h = 0; h < 2; ++h) {
                bshort8 B = *(const bshort8*)(w3b + (((nt * 9 + p) * 2 + h) * 64 + l) * 8);
                int q = h * 4 + kg;
                const char* base = arr + ((q * 11 + 2 * yb + ky) * 9 + xi3) * 16;
                if (two) {
                    bshort8 A0 = *(const bshort8*)(base);
                    c3a = __builtin_amdgcn_mfma_f32_16x16x32_bf16(A0, B, c3a, 0, 0, 0);
                    bshort8 A2 = *(const bshort8*)(base + 1152);
                    c3b = __builtin_amdgcn_mfma_f32_16x16x32_bf16(A2, B, c3b, 0, 0, 0);
                } else {
                    bshort8 A1 = *(const bshort8*)(base + 576);
                    c3a = __builtin_amdgcn_mfma_f32_16x16x32_bf16(A1, B, c3a, 0, 0, 0);
                }
            }
        }
        __syncthreads();
        float* sb = (float*)smraw;
        int oc = nt * 16 + m;
        float bv = b3[oc];
        int ob40 = oc * 40;
        if (two) {
#pragma unroll
            for (int reg = 0; reg < 4; ++reg) {
                sb[ob40 + kg * 4 + reg] = fmaxf(c3a[reg] + bv, 0.f);
                int px2 = 32 + kg * 4 + reg;
                if (px2 < 40) sb[ob40 + px2] = fmaxf(c3b[reg] + bv, 0.f);
            }
        } else {
#pragma unroll
            for (int reg = 0; reg < 4; ++reg)
                sb[ob40 + 16 + kg * 4 + reg] = fmaxf(c3a[reg] + bv, 0.f);
        }
        __syncthreads();
        for (int i = t; i < 1283; i += 256)
            seq[(long)img * 1283 + i] = (i < 1280) ? sb[i] : relpos[img * 3 + (i - 1280)];
    }
}

// ---------------------------------------------------------------------------
// Sensory (verbatim): pair-blocked, 256 blocks x 768 thr, 48KB LDS.
// ---------------------------------------------------------------------------
__global__ __launch_bounds__(768) void sensory_kernel(
    const float* __restrict__ sp, const float* __restrict__ seq,
    const float* __restrict__ iw, const float* __restrict__ ibias,
    float2* __restrict__ part) {
    const float4* P4 = (const float4*)sp;
    __shared__ __align__(16) char sbuf[49152];
    float*  IT  = (float*)sbuf;
    float2* red = (float2*)sbuf;
    const int t = threadIdx.x;
    const int pb = blockIdx.x * 8;

    for (int p = 0; p < 8; ++p)
        for (int k = t; k < 1283; k += 768)
            IT[k * 8 + p] = fmaf(seq[(long)(pb + p) * 1283 + k], iw[k], ibias[k]);
    __syncthreads();

    const int u = t % 48, kg = t / 48;
    float2 acc[8];
#pragma unroll
    for (int p = 0; p < 8; ++p) acc[p] = make_float2(0.f, 0.f);

#pragma unroll 2
    for (int i = 0; i < 81; ++i) {
        int k = kg + 16 * i;
        if (k < 1283) {
            float4 pv = P4[k * 48 + u];
            float4 Ia = *(const float4*)&IT[k * 8];
            float4 Ib = *(const float4*)&IT[k * 8 + 4];
            float r0 = __builtin_amdgcn_rcpf(1.f + __builtin_amdgcn_exp2f(fmaf(pv.x, Ia.x, pv.y)));
            float r1 = __builtin_amdgcn_rcpf(1.f + __builtin_amdgcn_exp2f(fmaf(pv.x, Ia.y, pv.y)));
            float r2 = __builtin_amdgcn_rcpf(1.f + __builtin_amdgcn_exp2f(fmaf(pv.x, Ia.z, pv.y)));
            float r3 = __builtin_amdgcn_rcpf(1.f + __builtin_amdgcn_exp2f(fmaf(pv.x, Ia.w, pv.y)));
            float r4 = __builtin_amdgcn_rcpf(1.f + __builtin_amdgcn_exp2f(fmaf(pv.x, Ib.x, pv.y)));
            float r5 = __builtin_amdgcn_rcpf(1.f + __builtin_amdgcn_exp2f(fmaf(pv.x, Ib.y, pv.y)));
            float r6 = __builtin_amdgcn_rcpf(1.f + __builtin_amdgcn_exp2f(fmaf(pv.x, Ib.z, pv.y)));
            float r7 = __builtin_amdgcn_rcpf(1.f + __builtin_amdgcn_exp2f(fmaf(pv.x, Ib.w, pv.y)));
            acc[0].x = fmaf(pv.z, r0, acc[0].x); acc[0].y = fmaf(pv.w, r0, acc[0].y);
            acc[1].x = fmaf(pv.z, r1, acc[1].x); acc[1].y = fmaf(pv.w, r1, acc[1].y);
            acc[2].x = fmaf(pv.z, r2, acc[2].x); acc[2].y = fmaf(pv.w, r2, acc[2].y);
            acc[3].x = fmaf(pv.z, r3, acc[3].x); acc[3].y = fmaf(pv.w, r3, acc[3].y);
            acc[4].x = fmaf(pv.z, r4, acc[4].x); acc[4].y = fmaf(pv.w, r4, acc[4].y);
            acc[5].x = fmaf(pv.z, r5, acc[5].x); acc[5].y = fmaf(pv.w, r5, acc[5].y);
            acc[6].x = fmaf(pv.z, r6, acc[6].x); acc[6].y = fmaf(pv.w, r6, acc[6].y);
            acc[7].x = fmaf(pv.z, r7, acc[7].x); acc[7].y = fmaf(pv.w, r7, acc[7].y);
        }
    }
    __syncthreads();
#pragma unroll
    for (int p = 0; p < 8; ++p) red[(kg * 8 + p) * 48 + u] = acc[p];
    __syncthreads();
    if (t < 384) {
        int p = t / 48, uu = t - p * 48;
        float sn = 0.f, sd = 0.f;
#pragma unroll
        for (int g = 0; g < 16; ++g) {
            float2 rr = red[(g * 8 + p) * 48 + uu];
            sn += rr.x; sd += rr.y;
        }
        part[(long)(pb + p) * 48 + uu] = make_float2(sn, sd);
    }
}

// ---------------------------------------------------------------------------
// Recurrent v8 (2nd resubmit — rounds 7/8 were infra failures, never ran):
// v6's proven 3-wave structure + IN-LANE interleave of 2 independent batch
// chains (32 blocks x 192 thr, 2 batches/block in the SAME lanes).
// Why: v6's 730cy/unfold = ~370cy fixed (barrier arrival + LDS write->read
// round trip) + ~360cy work. Advancing two chains per barrier period pays
// the fixed cost once per 2 unfolds; the param table P[12] is shared by
// both chains (no extra register pressure for params). Unlike failed v4
// (2 batches in separate wave-groups -> 6-wave barrier, no amortization),
// the barrier here still spans only 3 waves.
// Falsifier: recurrent > 62us -> revert to v6 verbatim, attack sensory.
// ---------------------------------------------------------------------------
__global__ __launch_bounds__(192, 1) void recurrent_kernel(
    const float* __restrict__ rp, const float* __restrict__ cmglv,
    const float2* __restrict__ part,
    const float* __restrict__ out_w, const float* __restrict__ out_b,
    const float* __restrict__ head_w, const float* __restrict__ head_b,
    float* __restrict__ outp) {
    __shared__ float2 WL[2][1536];     // sensory partials, 2 batches (24 KB)
    __shared__ float  LV[2][2][64];    // [batch][buf][u] v double-buffer
    __shared__ float  ym[2][4];
    const int t  = threadIdx.x;        // 0..191
    const int bA = blockIdx.x * 2;     // batches bA, bA+1
    const int u  = t >> 2;             // 0..47
    const int jq = t & 3;              // j-quarter

    // shared params in registers: j = jq*12 + r, dense [j][u64] float4 table
    const float4* RP4 = (const float4*)rp;
    float4 P[12];
#pragma unroll
    for (int r = 0; r < 12; ++r) P[r] = RP4[(jq * 12 + r) * 64 + u];
#pragma unroll
    for (int r = 0; r < 12; ++r) {
        asm volatile("" : "+v"(P[r].x), "+v"(P[r].y), "+v"(P[r].z), "+v"(P[r].w));
    }

    // stage sensory partials for both batches
    for (int i = t; i < 3072; i += 192) {
        int lb = i / 1536, li = i - lb * 1536;
        WL[lb][li] = part[(long)(bA + lb) * 1536 + li];
    }
    if (t < 64) { LV[0][0][t] = 0.f; LV[0][1][t] = 0.f; LV[1][0][t] = 0.f; LV[1][1][t] = 0.f; }

    const float cmt = cmglv[u], gl = cmglv[64 + u], glv = cmglv[128 + u];
    const float cg  = cmt + gl + 1e-8f;
    float ow = 0.f, ob = 0.f;
    const bool lead = (jq == 0) && (u < 4);
    if (lead) { ow = out_w[u]; ob = out_b[u]; }
    __syncthreads();

    float vnA = 0.f, vnB = 0.f, yaccA = 0.f, yaccB = 0.f;
    int buf = 0;
#pragma unroll 1
    for (int s = 0; s < 32; ++s) {
        float2 wA = WL[0][s * 48 + u];
        float2 wB = WL[1][s * 48 + u];
        const float basenA = glv + wA.x, basedA = cg + wA.y;
        const float basenB = glv + wB.x, basedB = cg + wB.y;
#pragma unroll
        for (int unf = 0; unf < 6; ++unf) {
            const float4* lvA = (const float4*)&LV[0][buf][jq * 12];
            const float4* lvB = (const float4*)&LV[1][buf][jq * 12];
            float4 A0 = lvA[0], A1 = lvA[1], A2 = lvA[2];
            float4 B0 = lvB[0], B1 = lvB[1], B2 = lvB[2];
            float vaA[12] = {A0.x, A0.y, A0.z, A0.w, A1.x, A1.y, A1.z, A1.w,
                             A2.x, A2.y, A2.z, A2.w};
            float vaB[12] = {B0.x, B0.y, B0.z, B0.w, B1.x, B1.y, B1.z, B1.w,
                             B2.x, B2.y, B2.z, B2.w};
            float pnA = 0.f, pdA = 0.f, pnB = 0.f, pdB = 0.f;
#pragma unroll
            for (int r = 0; r < 12; ++r) {
                float rA = __builtin_amdgcn_rcpf(
                    1.f + __builtin_amdgcn_exp2f(fmaf(P[r].x, vaA[r], P[r].y)));
                float rB = __builtin_amdgcn_rcpf(
                    1.f + __builtin_amdgcn_exp2f(fmaf(P[r].x, vaB[r], P[r].y)));
                pnA = fmaf(P[r].z, rA, pnA); pdA = fmaf(P[r].w, rA, pdA);
                pnB = fmaf(P[r].z, rB, pnB); pdB = fmaf(P[r].w, rB, pdB);
            }
            // quad reduce over 4 j-quarters (DPP, all-VALU)
            pnA += qxor1_(pnA); pdA += qxor1_(pdA);
            pnB += qxor1_(pnB); pdB += qxor1_(pdB);
            pnA += qxor2_(pnA); pdA += qxor2_(pdA);
            pnB += qxor2_(pnB); pdB += qxor2_(pdB);
            float numA = fmaf(cmt, vnA, basenA) + pnA;
            float denA = basedA + pdA;
            float numB = fmaf(cmt, vnB, basenB) + pnB;
            float denB = basedB + pdB;
            float rA0 = __builtin_amdgcn_rcpf(denA);
            rA0 = rA0 * fmaf(-denA, rA0, 2.f);      // 1 Newton step: ~1 ulp
            float rB0 = __builtin_amdgcn_rcpf(denB);
            rB0 = rB0 * fmaf(-denB, rB0, 2.f);
            vnA = numA * rA0;
            vnB = numB * rB0;
            if (jq == 0) { LV[0][buf ^ 1][u] = vnA; LV[1][buf ^ 1][u] = vnB; }
            __syncthreads();
            buf ^= 1;
        }
        if (lead) { yaccA = fmaf(vnA, ow, yaccA) + ob; yaccB = fmaf(vnB, ow, yaccB) + ob; }
    }
    if (lead) { ym[0][u] = yaccA; ym[1][u] = yaccB; }
    __syncthreads();
    if (t < 4) {
        int lb = t >> 1, g = t & 1;
        const float inv = 1.f / 32.f;
        float o = fmaf(ym[lb][0] * inv, head_w[g],
                  fmaf(ym[lb][1] * inv, head_w[2 + g],
                  fmaf(ym[lb][2] * inv, head_w[4 + g],
                  fmaf(ym[lb][3] * inv, head_w[6 + g], head_b[g]))));
        outp[(bA + lb) * 2 + g] = tanhf(o);
    }
}

extern "C" void kernel_launch(void* const* d_in, const int* in_sizes, int n_in,
                              void* d_out, int out_size, void* d_ws, size_t ws_size,
                              hipStream_t stream) {
    const float* depth      = (const float*)d_in[0];
    const float* relpos     = (const float*)d_in[1];
    const float* w1         = (const float*)d_in[2];
    const float* b1         = (const float*)d_in[3];
    const float* w2         = (const float*)d_in[4];
    const float* b2         = (const float*)d_in[5];
    const float* w3         = (const float*)d_in[6];
    const float* b3         = (const float*)d_in[7];
    const float* iw         = (const float*)d_in[8];
    const float* ibias      = (const float*)d_in[9];
    const float* sens_w     = (const float*)d_in[10];
    const float* sens_mu    = (const float*)d_in[11];
    const float* sens_sigma = (const float*)d_in[12];
    const float* sens_erev  = (const float*)d_in[13];
    const float* rec_w      = (const float*)d_in[14];
    const float* rec_mu     = (const float*)d_in[15];
    const float* rec_sigma  = (const float*)d_in[16];
    const float* rec_erev   = (const float*)d_in[17];
    const float* gleak      = (const float*)d_in[18];
    const float* vleak      = (const float*)d_in[19];
    const float* cm         = (const float*)d_in[20];
    const float* out_w      = (const float*)d_in[21];
    const float* out_b      = (const float*)d_in[22];
    const float* head_w     = (const float*)d_in[23];
    const float* head_b     = (const float*)d_in[24];
    const int*   sens_mask  = (const int*)d_in[25];
    const int*   rec_mask   = (const int*)d_in[26];

    float* ws  = (float*)d_ws;
    float* out = (float*)d_out;

    prep_kernel<<<477, 256, 0, stream>>>(sens_w, sens_mu, sens_sigma, sens_erev, sens_mask,
                                         rec_w, rec_mu, rec_sigma, rec_erev, rec_mask,
                                         gleak, vleak, cm, w2, w3, ws);
    cnn_kernel<<<2048, 256, 0, stream>>>(depth, relpos, w1, b1, b2, b3,
                                         (const __hip_bfloat16*)(ws + OFF_W2B),
                                         (const __hip_bfloat16*)(ws + OFF_W3B),
                                         ws + OFF_SEQ);
    sensory_kernel<<<256, 768, 0, stream>>>(ws + OFF_SP4, ws + OFF_SEQ, iw, ibias,
                                            (float2*)(ws + OFF_PART));
    recurrent_kernel<<<32, 192, 0, stream>>>(ws + OFF_RP4, ws + OFF_CM,
                                             (const float2*)(ws + OFF_PART),
                                             out_w, out_b, head_w, head_b, out);
}

// Round 10
// 261.368 us; speedup vs baseline: 1.4970x; 1.1903x over previous
//
#include <hip/hip_runtime.h>
#include <hip/hip_bf16.h>

// Shapes: B=64 S=32 H=40 W=64 ; conv1: 1->32 (20x32) ; conv2: 32->64 (10x16) ; conv3: 64->32 (5x8)
// SENS=1283 UNITS=48 MOTOR=4 NA=2 UNFOLDS=6

typedef __attribute__((ext_vector_type(8))) short bshort8;   // 8 bf16 (4 VGPR) MFMA frag
typedef __attribute__((ext_vector_type(4))) float f32x4;     // MFMA acc

// ---- workspace layout (float units) ----
constexpr long OFF_SEQ  = 0;                 // 2048*1283 = 2627584
constexpr long OFF_SP4  = 2627584;           // sensory COMPACT region (122928 of 246336 fl):
                                             //   [0,98304)        float4 cp4[480][48]
                                             //   [98304,122880)   int    kix[480][48]
                                             //   [122880,122928)  int    nnz[48] (debug)
constexpr long OFF_RP4  = 2873920;           // rec params float4[48 j][64 u-padded] = 12288 fl
constexpr long OFF_CM   = 2886208;           // cm_t(64), gl(64), gl*vleak(64)
constexpr long OFF_W2B  = 2886400;           // conv2 bf16 frags (K-repacked): 24576 bf16 = 12288 fl
constexpr long OFF_W3B  = 2898688;           // conv3 bf16 frags: 18432 bf16 = 9216 fl
constexpr long OFF_PART = 2907904;           // float2[2048*48] = 196608 fl
// end 3104512 fl = 12.42 MB

constexpr int SCAP = 480;   // sensory compact capacity: mean nnz 385, sd 16.4 -> +5.8 sigma

__device__ __forceinline__ float sp_(float x) {
    return fmaxf(x, 0.f) + log1pf(expf(-fabsf(x)));   // stable softplus
}

// quad-lane XOR reduce helpers via DPP quad_perm (VALU-speed, no LDS pipe).
__device__ __forceinline__ float qxor1_(float x) {
    return __int_as_float(__builtin_amdgcn_mov_dpp(__float_as_int(x), 0xB1, 0xF, 0xF, true));
}
__device__ __forceinline__ float qxor2_(float x) {
    return __int_as_float(__builtin_amdgcn_mov_dpp(__float_as_int(x), 0x4E, 0xF, 0xF, true));
}

// ---------------------------------------------------------------------------
// prep: rec/cm/w2b/w3b sections verbatim from the proven version. The dense
// sensory section is REMOVED (replaced by sens_compact_kernel below); the
// index space starts at 61584 so all other section thresholds are unchanged.
// ---------------------------------------------------------------------------
__global__ void prep_kernel(const float* __restrict__ rec_w, const float* __restrict__ rec_mu,
                            const float* __restrict__ rec_sigma, const float* __restrict__ rec_erev,
                            const int* __restrict__ rec_mask,
                            const float* __restrict__ gleak, const float* __restrict__ vleak,
                            const float* __restrict__ cm,
                            const float* __restrict__ w2, const float* __restrict__ w3,
                            float* __restrict__ ws) {
    const float L2E = 1.4426950408889634f;
    int i = blockIdx.x * 256 + threadIdx.x + 61584;
    if (i < 64656) {                       // recurrent: [j 48][u 64 padded]
        int q = i - 61584;
        int j = q >> 6, u = q & 63;
        float4 v = make_float4(0.f, 0.f, 0.f, 0.f);
        if (u < 48) {
            int idx = j * 48 + u;
            float m  = rec_mask[idx] ? 1.f : 0.f;
            float sw = sp_(rec_w[idx]) * m;
            float sg = rec_sigma[idx], mu = rec_mu[idx];
            v = make_float4(-sg * L2E, sg * mu * L2E, sw * rec_erev[idx], sw);
        }
        ((float4*)(ws + OFF_RP4))[q] = v;
    } else if (i < 64704) {
        int u = i - 64656;                 // u < 48
        float g = sp_(gleak[u]);
        ws[OFF_CM + u]       = sp_(cm[u]) * 6.f;
        ws[OFF_CM + 64 + u]  = g;
        ws[OFF_CM + 128 + u] = g * vleak[u];
    } else if (i < 89280) {                // w2b K-repacked frags (24576)
        int n = i - 64704;
        int j = n & 7, l = (n >> 3) & 63, t2 = n >> 9;   // t2 0..47
        int wv = t2 & 3;
        int r  = t2 >> 2;                  // 0..11 = (h*3+ky)*2+xp
        int xp = r & 1, hk = r >> 1;       // hk = h*3+ky
        int ky = hk % 3, h = hk / 3;
        int oc = wv * 16 + (l & 15);
        int kgB = l >> 4;
        int icl = (kgB & 1) * 8 + j;
        int ic = h * 16 + icl;
        int kx = 2 * xp + (kgB >> 1);
        float val = (kx == 3) ? 0.f : w2[((oc * 32 + ic) * 3 + ky) * 3 + kx];
        ((__hip_bfloat16*)(ws + OFF_W2B))[n] = __float2bfloat16(val);
    } else if (i < 107712) {               // w3b frags (unchanged mapping)
        int n = i - 89280;
        int j = n & 7, l = (n >> 3) & 63, t3 = n >> 9;
        int h = t3 & 1, u2 = t3 >> 1;
        int nt = u2 / 9, p = u2 % 9;
        int ky = p / 3, kx = p % 3;
        int oc = nt * 16 + (l & 15);
        int ic = h * 32 + (l >> 4) * 8 + j;
        ((__hip_bfloat16*)(ws + OFF_W3B))[n] =
            __float2bfloat16(w3[((oc * 64 + ic) * 3 + ky) * 3 + kx]);
    }
}

// ---------------------------------------------------------------------------
// sens_compact: per-u compaction of the ~30%-dense sensory wiring.
// Block = u (48 blocks x 256 thr). Deterministic ballot/prefix scan keeps
// k-ascending order. Padded entries are all-zero params -> contribute
// exactly 0 (same exactness argument as R1's validated rec compaction).
// ---------------------------------------------------------------------------
__global__ __launch_bounds__(256) void sens_compact_kernel(
    const float* __restrict__ sens_w, const float* __restrict__ sens_mu,
    const float* __restrict__ sens_sigma, const float* __restrict__ sens_erev,
    const int* __restrict__ sens_mask, float* __restrict__ ws) {
    const float L2E = 1.4426950408889634f;
    float4* cp4 = (float4*)(ws + OFF_SP4);
    int* kix = (int*)(ws + OFF_SP4 + 98304);
    int* nnz = (int*)(ws + OFF_SP4 + 122880);
    const int u = blockIdx.x;          // 0..47
    const int t = threadIdx.x;         // 0..255
    const int w = t >> 6, lane = t & 63;
    __shared__ int wcnt[4];
    __shared__ int basetot;
    if (t == 0) basetot = 0;
    __syncthreads();
#pragma unroll 1
    for (int c = 0; c < 6; ++c) {
        int k = c * 256 + t;
        bool m = (k < 1283) && (sens_mask[k * 48 + u] != 0);
        unsigned long long bal = __ballot(m);
        int prefix = __popcll(bal & ((1ULL << lane) - 1ULL));
        if (lane == 0) wcnt[w] = __popcll(bal);
        __syncthreads();                                   // wcnt visible
        int wbase = basetot;
        for (int ww = 0; ww < 4; ++ww) if (ww < w) wbase += wcnt[ww];
        if (m) {
            int pos = wbase + prefix;
            if (pos < SCAP) {
                int idx = k * 48 + u;
                float sw = sp_(sens_w[idx]);
                float sg = sens_sigma[idx], mu = sens_mu[idx];
                cp4[pos * 48 + u] = make_float4(-sg * L2E, sg * mu * L2E,
                                                sw * sens_erev[idx], sw);
                kix[pos * 48 + u] = k;
            }
        }
        __syncthreads();                                   // all used wcnt/basetot
        if (t == 0) basetot += wcnt[0] + wcnt[1] + wcnt[2] + wcnt[3];
        __syncthreads();                                   // basetot updated
    }
    int cnt = min(basetot, SCAP);
    for (int e = cnt + t; e < SCAP; e += 256) {            // zero-pad tail
        cp4[e * 48 + u] = make_float4(0.f, 0.f, 0.f, 0.f);
        kix[e * 48 + u] = 0;
    }
    if (t == 0) nnz[u] = cnt;
}

// ---------------------------------------------------------------------------
// Fused CNN (verbatim from the 294.7us best).
// ---------------------------------------------------------------------------
#define IMGB 0
#define C1H  5424
#define A2E  0
#define A2O  12672
#define SMB  28272

__global__ __launch_bounds__(256, 4) void cnn_kernel(
    const float* __restrict__ depth, const float* __restrict__ relpos,
    const float* __restrict__ w1, const float* __restrict__ b1,
    const float* __restrict__ b2, const float* __restrict__ b3,
    const __hip_bfloat16* __restrict__ w2b, const __hip_bfloat16* __restrict__ w3b,
    float* __restrict__ seq) {
    __shared__ __align__(16) char smraw[SMB];
    const int t = threadIdx.x;
    const int img = blockIdx.x;
    const int l = t & 63;
    const int wvu = __builtin_amdgcn_readfirstlane(t >> 6);
    const int m = l & 15, kg = l >> 4;

    for (int i = t; i < 7068; i += 256) ((uint*)smraw)[i] = 0u;
    __syncthreads();
    for (int i = t; i < 1280; i += 256) {
        int pos = 2 * i;
        int h = pos >> 6, w = pos & 63;
        float2 d = *(const float2*)(depth + (long)img * 2560 + pos);
        __hip_bfloat162 pk = __float22bfloat162_rn(d);
        *(__hip_bfloat162*)(smraw + IMGB + ((h + 1) * 66 + (w + 2)) * 2) = pk;
    }
    __syncthreads();

    const __hip_bfloat16* imgp = (const __hip_bfloat16*)(smraw + IMGB);
    f32x4 acc[10];
    {
        float bias = b2[wvu * 16 + m];
#pragma unroll
        for (int mt = 0; mt < 10; ++mt) acc[mt] = (f32x4){bias, bias, bias, bias};
    }

#pragma unroll 1
    for (int h = 0; h < 2; ++h) {
        const int ocb = h * 16 + wvu * 4;      // uniform
        float wv4[4][9], bv4[4];
#pragma unroll
        for (int j = 0; j < 4; ++j) {
            bv4[j] = b1[ocb + j];
#pragma unroll
            for (int k = 0; k < 9; ++k) wv4[j][k] = w1[(ocb + j) * 9 + k];
        }
#pragma unroll 1
        for (int i = 0; i < 10; ++i) {
            int p = l + (i << 6);
            int y1 = p >> 5, x1 = p & 31;
            float xin[9];
#pragma unroll
            for (int ky = 0; ky < 3; ++ky)
#pragma unroll
                for (int kx = 0; kx < 3; ++kx)
                    xin[ky * 3 + kx] = __bfloat162float(imgp[(2 * y1 + ky) * 66 + 2 * x1 + kx + 1]);
            float o[4];
#pragma unroll
            for (int j = 0; j < 4; ++j) {
                float a = bv4[j];
#pragma unroll
                for (int k = 0; k < 9; ++k) a = fmaf(wv4[j][k], xin[k], a);
                o[j] = fmaxf(a, 0.f);
            }
            char* cb = smraw + C1H + (((y1 + 1) * 34) + (x1 + 1)) * 32 + wvu * 8;
            *(__hip_bfloat162*)cb       = __float22bfloat162_rn(make_float2(o[0], o[1]));
            *(__hip_bfloat162*)(cb + 4) = __float22bfloat162_rn(make_float2(o[2], o[3]));
        }
        bshort8 Bh[6];
#pragma unroll
        for (int f = 0; f < 6; ++f)
            Bh[f] = *(const bshort8*)(w2b + (((h * 6 + f) * 4 + wvu) * 64 + l) * 8);
        __syncthreads();   // c1h pass-h ready
#pragma unroll
        for (int ky = 0; ky < 3; ++ky) {
#pragma unroll
            for (int xp = 0; xp < 2; ++xp) {
                bshort8 Bp = Bh[ky * 2 + xp];
                const char* base = smraw + C1H + (ky * 34 + 2 * m + 2 * xp + (kg >> 1)) * 32 + (kg & 1) * 16;
#pragma unroll
                for (int mt = 0; mt < 10; ++mt) {
                    bshort8 A = *(const bshort8*)(base + mt * 2176);   // 2 rows * 34 cols * 32 B
                    acc[mt] = __builtin_amdgcn_mfma_f32_16x16x32_bf16(A, Bp, acc[mt], 0, 0, 0);
                }
            }
        }
        __syncthreads();   // reads done before next conv1 overwrite / a2 overlay
    }

    for (int i = t; i < 6336; i += 256) ((uint*)smraw)[i] = 0u;
    __syncthreads();
    {
        int oc = wvu * 16 + m;
        int q = oc >> 3, sub = oc & 7;
#pragma unroll
        for (int mt = 0; mt < 10; ++mt) {
            int row = mt + 1;
#pragma unroll
            for (int reg = 0; reg < 4; ++reg) {
                int x2 = kg * 4 + reg;
                int odd = x2 & 1;
                int xi = odd ? ((x2 + 1) >> 1) : (x2 >> 1);
                char* ab = smraw + (odd ? A2O : A2E);
                float v = fmaxf(acc[mt][reg], 0.f);
                *(__hip_bfloat16*)(ab + (((q * 11 + row) * 9 + xi) * 8 + sub) * 2) = __float2bfloat16(v);
            }
        }
    }
    __syncthreads();

    {
        const int nt = wvu & 1;
        const bool two = wvu < 2;
        f32x4 c3a = (f32x4){0.f, 0.f, 0.f, 0.f};
        f32x4 c3b = (f32x4){0.f, 0.f, 0.f, 0.f};
        const int xb = m & 7, yb = m >> 3;
#pragma unroll
        for (int p = 0; p < 9; ++p) {
            int ky = p / 3, kx = p % 3;
            const char* arr = smraw + ((kx == 1) ? A2E : A2O);
            int xi3 = xb + (kx == 2);
#pragma unroll
            for (int h = 0; h < 2; ++h) {
                bshort8 B = *(const bshort8*)(w3b + (((nt * 9 + p) * 2 + h) * 64 + l) * 8);
                int q = h * 4 + kg;
                const char* base = arr + ((q * 11 + 2 * yb + ky) * 9 + xi3) * 16;
                if (two) {
                    bshort8 A0 = *(const bshort8*)(base);
                    c3a = __builtin_amdgcn_mfma_f32_16x16x32_bf16(A0, B, c3a, 0, 0, 0);
                    bshort8 A2 = *(const bshort8*)(base + 1152);
                    c3b = __builtin_amdgcn_mfma_f32_16x16x32_bf16(A2, B, c3b, 0, 0, 0);
                } else {
                    bshort8 A1 = *(const bshort8*)(base + 576);
                    c3a = __builtin_amdgcn_mfma_f32_16x16x32_bf16(A1, B, c3a, 0, 0, 0);
                }
            }
        }
        __syncthreads();
        float* sb = (float*)smraw;
        int oc = nt * 16 + m;
        float bv = b3[oc];
        int ob40 = oc * 40;
        if (two) {
#pragma unroll
            for (int reg = 0; reg < 4; ++reg) {
                sb[ob40 + kg * 4 + reg] = fmaxf(c3a[reg] + bv, 0.f);
                int px2 = 32 + kg * 4 + reg;
                if (px2 < 40) sb[ob40 + px2] = fmaxf(c3b[reg] + bv, 0.f);
            }
        } else {
#pragma unroll
            for (int reg = 0; reg < 4; ++reg)
                sb[ob40 + 16 + kg * 4 + reg] = fmaxf(c3a[reg] + bv, 0.f);
        }
        __syncthreads();
        for (int i = t; i < 1283; i += 256)
            seq[(long)img * 1283 + i] = (i < 1280) ? sb[i] : relpos[img * 3 + (i - 1280)];
    }
}

// ---------------------------------------------------------------------------
// Sensory v2 (SPARSE): loops the prep-compacted nonzero list (480-cap vs
// 1283 dense = 30 vs 81 iters/thread; ~2.7x less trans work + table traffic
// 3.9MB -> 369KB, L2-resident). I-values staged TRANSPOSED in LDS
// ([p][k], pitch 1288) so the per-entry k-gather is 8 scalar ds_read_b32
// with random-k bank spread (~2 lanes/bank = free) instead of a 4-bank
// clustered b128 gather. Reduction stage unchanged.
// ---------------------------------------------------------------------------
__global__ __launch_bounds__(768) void sensory_kernel(
    const float* __restrict__ sp, const float* __restrict__ seq,
    const float* __restrict__ iw, const float* __restrict__ ibias,
    float2* __restrict__ part) {
    const float4* CP4 = (const float4*)sp;
    const int* KIX = (const int*)(sp + 98304);
    __shared__ __align__(16) char sbuf[49152];
    float*  IT  = (float*)sbuf;        // [8][1288] transposed I-table (41216 B)
    float2* red = (float2*)sbuf;       // reused after compute barrier
    const int t = threadIdx.x;
    const int pb = blockIdx.x * 8;

    for (int p = 0; p < 8; ++p)
        for (int k = t; k < 1283; k += 768)
            IT[p * 1288 + k] = fmaf(seq[(long)(pb + p) * 1283 + k], iw[k], ibias[k]);
    __syncthreads();

    const int u = t % 48, kg = t / 48;
    float2 acc[8];
#pragma unroll
    for (int p = 0; p < 8; ++p) acc[p] = make_float2(0.f, 0.f);

#pragma unroll 2
    for (int i = 0; i < 30; ++i) {
        int e = kg + 16 * i;                       // covers 0..479 exactly
        float4 pv = CP4[e * 48 + u];               // coalesced over u
        int k = KIX[e * 48 + u];
        const float* itk = IT + k;
        float r0 = __builtin_amdgcn_rcpf(1.f + __builtin_amdgcn_exp2f(fmaf(pv.x, itk[0 * 1288], pv.y)));
        float r1 = __builtin_amdgcn_rcpf(1.f + __builtin_amdgcn_exp2f(fmaf(pv.x, itk[1 * 1288], pv.y)));
        float r2 = __builtin_amdgcn_rcpf(1.f + __builtin_amdgcn_exp2f(fmaf(pv.x, itk[2 * 1288], pv.y)));
        float r3 = __builtin_amdgcn_rcpf(1.f + __builtin_amdgcn_exp2f(fmaf(pv.x, itk[3 * 1288], pv.y)));
        float r4 = __builtin_amdgcn_rcpf(1.f + __builtin_amdgcn_exp2f(fmaf(pv.x, itk[4 * 1288], pv.y)));
        float r5 = __builtin_amdgcn_rcpf(1.f + __builtin_amdgcn_exp2f(fmaf(pv.x, itk[5 * 1288], pv.y)));
        float r6 = __builtin_amdgcn_rcpf(1.f + __builtin_amdgcn_exp2f(fmaf(pv.x, itk[6 * 1288], pv.y)));
        float r7 = __builtin_amdgcn_rcpf(1.f + __builtin_amdgcn_exp2f(fmaf(pv.x, itk[7 * 1288], pv.y)));
        acc[0].x = fmaf(pv.z, r0, acc[0].x); acc[0].y = fmaf(pv.w, r0, acc[0].y);
        acc[1].x = fmaf(pv.z, r1, acc[1].x); acc[1].y = fmaf(pv.w, r1, acc[1].y);
        acc[2].x = fmaf(pv.z, r2, acc[2].x); acc[2].y = fmaf(pv.w, r2, acc[2].y);
        acc[3].x = fmaf(pv.z, r3, acc[3].x); acc[3].y = fmaf(pv.w, r3, acc[3].y);
        acc[4].x = fmaf(pv.z, r4, acc[4].x); acc[4].y = fmaf(pv.w, r4, acc[4].y);
        acc[5].x = fmaf(pv.z, r5, acc[5].x); acc[5].y = fmaf(pv.w, r5, acc[5].y);
        acc[6].x = fmaf(pv.z, r6, acc[6].x); acc[6].y = fmaf(pv.w, r6, acc[6].y);
        acc[7].x = fmaf(pv.z, r7, acc[7].x); acc[7].y = fmaf(pv.w, r7, acc[7].y);
    }
    __syncthreads();   // IT reads done; region reused as red
#pragma unroll
    for (int p = 0; p < 8; ++p) red[(kg * 8 + p) * 48 + u] = acc[p];
    __syncthreads();
    if (t < 384) {
        int p = t / 48, uu = t - p * 48;
        float sn = 0.f, sd = 0.f;
#pragma unroll
        for (int g = 0; g < 16; ++g) {
            float2 rr = red[(g * 8 + p) * 48 + uu];
            sn += rr.x; sd += rr.y;
        }
        part[(long)(pb + p) * 48 + uu] = make_float2(sn, sd);
    }
}

// ---------------------------------------------------------------------------
// Recurrent v6 VERBATIM (67.0us measured in R5 — best of 6 structures tried;
// v8's in-lane dual chain regressed to 102.6: the unfold cost is the
// dependent chain, not a fixed barrier cost, so a second chain adds its
// full serial length). 64 blocks x 192 thr, 1 batch/block, 3-wave barrier.
// ---------------------------------------------------------------------------
__global__ __launch_bounds__(192, 1) void recurrent_kernel(
    const float* __restrict__ rp, const float* __restrict__ cmglv,
    const float2* __restrict__ part,
    const float* __restrict__ out_w, const float* __restrict__ out_b,
    const float* __restrict__ head_w, const float* __restrict__ head_b,
    float* __restrict__ outp) {
    __shared__ float2 WL[1536];        // sensory partials for this batch
    __shared__ float  LV[2][64];       // v double-buffer
    __shared__ float  ym[4];
    const int t  = threadIdx.x;        // 0..191
    const int b  = blockIdx.x;
    const int u  = t >> 2;             // 0..47
    const int jq = t & 3;              // j-quarter

    // params in registers: j = jq*12 + r, dense [j][u64] float4 table
    const float4* RP4 = (const float4*)rp;
    float4 P[12];
#pragma unroll
    for (int r = 0; r < 12; ++r) P[r] = RP4[(jq * 12 + r) * 64 + u];
#pragma unroll
    for (int r = 0; r < 12; ++r) {
        asm volatile("" : "+v"(P[r].x), "+v"(P[r].y), "+v"(P[r].z), "+v"(P[r].w));
    }

    // stage sensory partials for this batch
    for (int i = t; i < 1536; i += 192) WL[i] = part[(long)b * 1536 + i];
    if (t < 64) { LV[0][t] = 0.f; LV[1][t] = 0.f; }

    const float cmt = cmglv[u], gl = cmglv[64 + u], glv = cmglv[128 + u];
    const float cg  = cmt + gl + 1e-8f;
    float ow = 0.f, ob = 0.f;
    const bool lead = (jq == 0) && (u < 4);
    if (lead) { ow = out_w[u]; ob = out_b[u]; }
    __syncthreads();

    float vn = 0.f, yacc = 0.f;
    int buf = 0;
#pragma unroll 1
    for (int s = 0; s < 32; ++s) {
        float2 wnd = WL[s * 48 + u];
        const float basen = glv + wnd.x;       // per-step invariants
        const float based = cg + wnd.y;
#pragma unroll
        for (int unf = 0; unf < 6; ++unf) {
            const float4* lv4 = (const float4*)&LV[buf][jq * 12];
            float4 V0 = lv4[0], V1 = lv4[1], V2 = lv4[2];
            float va[12] = {V0.x, V0.y, V0.z, V0.w, V1.x, V1.y, V1.z, V1.w,
                            V2.x, V2.y, V2.z, V2.w};
            float pn = 0.f, pd = 0.f;
#pragma unroll
            for (int r = 0; r < 12; ++r) {
                float rr = __builtin_amdgcn_rcpf(
                    1.f + __builtin_amdgcn_exp2f(fmaf(P[r].x, va[r], P[r].y)));
                pn = fmaf(P[r].z, rr, pn);
                pd = fmaf(P[r].w, rr, pd);
            }
            // quad reduce over the 4 j-quarters: DPP quad_perm, all-VALU
            pn += qxor1_(pn); pd += qxor1_(pd);
            pn += qxor2_(pn); pd += qxor2_(pd);
            float num = fmaf(cmt, vn, basen) + pn;
            float den = based + pd;
            float r0 = __builtin_amdgcn_rcpf(den);
            r0 = r0 * fmaf(-den, r0, 2.f);       // 1 Newton step: ~1 ulp
            vn = num * r0;
            if (jq == 0) LV[buf ^ 1][u] = vn;
            __syncthreads();
            buf ^= 1;
        }
        if (lead) yacc = fmaf(vn, ow, yacc) + ob;
    }
    if (lead) ym[u] = yacc;
    __syncthreads();
    if (t < 2) {
        const float inv = 1.f / 32.f;
        float o = fmaf(ym[0] * inv, head_w[t],
                  fmaf(ym[1] * inv, head_w[2 + t],
                  fmaf(ym[2] * inv, head_w[4 + t],
                  fmaf(ym[3] * inv, head_w[6 + t], head_b[t]))));
        outp[b * 2 + t] = tanhf(o);
    }
}

extern "C" void kernel_launch(void* const* d_in, const int* in_sizes, int n_in,
                              void* d_out, int out_size, void* d_ws, size_t ws_size,
                              hipStream_t stream) {
    const float* depth      = (const float*)d_in[0];
    const float* relpos     = (const float*)d_in[1];
    const float* w1         = (const float*)d_in[2];
    const float* b1         = (const float*)d_in[3];
    const float* w2         = (const float*)d_in[4];
    const float* b2         = (const float*)d_in[5];
    const float* w3         = (const float*)d_in[6];
    const float* b3         = (const float*)d_in[7];
    const float* iw         = (const float*)d_in[8];
    const float* ibias      = (const float*)d_in[9];
    const float* sens_w     = (const float*)d_in[10];
    const float* sens_mu    = (const float*)d_in[11];
    const float* sens_sigma = (const float*)d_in[12];
    const float* sens_erev  = (const float*)d_in[13];
    const float* rec_w      = (const float*)d_in[14];
    const float* rec_mu     = (const float*)d_in[15];
    const float* rec_sigma  = (const float*)d_in[16];
    const float* rec_erev   = (const float*)d_in[17];
    const float* gleak      = (const float*)d_in[18];
    const float* vleak      = (const float*)d_in[19];
    const float* cm         = (const float*)d_in[20];
    const float* out_w      = (const float*)d_in[21];
    const float* out_b      = (const float*)d_in[22];
    const float* head_w     = (const float*)d_in[23];
    const float* head_b     = (const float*)d_in[24];
    const int*   sens_mask  = (const int*)d_in[25];
    const int*   rec_mask   = (const int*)d_in[26];

    float* ws  = (float*)d_ws;
    float* out = (float*)d_out;

    prep_kernel<<<181, 256, 0, stream>>>(rec_w, rec_mu, rec_sigma, rec_erev, rec_mask,
                                         gleak, vleak, cm, w2, w3, ws);
    sens_compact_kernel<<<48, 256, 0, stream>>>(sens_w, sens_mu, sens_sigma, sens_erev,
                                                sens_mask, ws);
    cnn_kernel<<<2048, 256, 0, stream>>>(depth, relpos, w1, b1, b2, b3,
                                         (const __hip_bfloat16*)(ws + OFF_W2B),
                                         (const __hip_bfloat16*)(ws + OFF_W3B),
                                         ws + OFF_SEQ);
    sensory_kernel<<<256, 768, 0, stream>>>(ws + OFF_SP4, ws + OFF_SEQ, iw, ibias,
                                            (float2*)(ws + OFF_PART));
    recurrent_kernel<<<64, 192, 0, stream>>>(ws + OFF_RP4, ws + OFF_CM,
                                             (const float2*)(ws + OFF_PART),
                                             out_w, out_b, head_w, head_b, out);
}

// Round 11
// 256.122 us; speedup vs baseline: 1.5277x; 1.0205x over previous
//
#include <hip/hip_runtime.h>
#include <hip/hip_bf16.h>

// Shapes: B=64 S=32 H=40 W=64 ; conv1: 1->32 (20x32) ; conv2: 32->64 (10x16) ; conv3: 64->32 (5x8)
// SENS=1283 UNITS=48 MOTOR=4 NA=2 UNFOLDS=6

typedef __attribute__((ext_vector_type(8))) short bshort8;   // 8 bf16 (4 VGPR) MFMA frag
typedef __attribute__((ext_vector_type(4))) float f32x4;     // MFMA acc

// ---- workspace layout (float units) ----
constexpr long OFF_SEQ  = 0;                 // 2048*1283 = 2627584
constexpr long OFF_SP4  = 2627584;           // sensory COMPACT region (122928 of 246336 fl):
                                             //   [0,98304)        float4 cp4[480][48]
                                             //   [98304,122880)   int    kix[480][48]
                                             //   [122880,122928)  int    nnz[48] (debug)
constexpr long OFF_RP4  = 2873920;           // rec params float4[48 j][64 u-padded] = 12288 fl
constexpr long OFF_CM   = 2886208;           // cm_t(64), gl(64), gl*vleak(64)
constexpr long OFF_W2B  = 2886400;           // conv2 bf16 frags (K-repacked): 24576 bf16 = 12288 fl
constexpr long OFF_W3B  = 2898688;           // conv3 bf16 frags: 18432 bf16 = 9216 fl
constexpr long OFF_PART = 2907904;           // float2[2048*48] = 196608 fl
// end 3104512 fl = 12.42 MB

constexpr int SCAP = 480;   // sensory compact capacity: mean nnz 385, sd 16.4 -> +5.8 sigma

__device__ __forceinline__ float sp_(float x) {
    return fmaxf(x, 0.f) + log1pf(expf(-fabsf(x)));   // stable softplus
}

// quad-lane XOR reduce helpers via DPP quad_perm (VALU-speed, no LDS pipe).
__device__ __forceinline__ float qxor1_(float x) {
    return __int_as_float(__builtin_amdgcn_mov_dpp(__float_as_int(x), 0xB1, 0xF, 0xF, true));
}
__device__ __forceinline__ float qxor2_(float x) {
    return __int_as_float(__builtin_amdgcn_mov_dpp(__float_as_int(x), 0x4E, 0xF, 0xF, true));
}

// ---------------------------------------------------------------------------
// prep (MERGED): blocks [0,181) = rec/cm/w2b/w3b sections (verbatim);
// blocks [181,229) = sensory compaction (one block per u, verbatim body).
// Merging removes one kernel launch from the serialized stream.
// ---------------------------------------------------------------------------
__global__ __launch_bounds__(256) void prep_kernel(
    const float* __restrict__ rec_w, const float* __restrict__ rec_mu,
    const float* __restrict__ rec_sigma, const float* __restrict__ rec_erev,
    const int* __restrict__ rec_mask,
    const float* __restrict__ gleak, const float* __restrict__ vleak,
    const float* __restrict__ cm,
    const float* __restrict__ w2, const float* __restrict__ w3,
    const float* __restrict__ sens_w, const float* __restrict__ sens_mu,
    const float* __restrict__ sens_sigma, const float* __restrict__ sens_erev,
    const int* __restrict__ sens_mask,
    float* __restrict__ ws) {
    const float L2E = 1.4426950408889634f;
    if (blockIdx.x < 181) {
        int i = blockIdx.x * 256 + threadIdx.x + 61584;
        if (i < 64656) {                       // recurrent: [j 48][u 64 padded]
            int q = i - 61584;
            int j = q >> 6, u = q & 63;
            float4 v = make_float4(0.f, 0.f, 0.f, 0.f);
            if (u < 48) {
                int idx = j * 48 + u;
                float m  = rec_mask[idx] ? 1.f : 0.f;
                float sw = sp_(rec_w[idx]) * m;
                float sg = rec_sigma[idx], mu = rec_mu[idx];
                v = make_float4(-sg * L2E, sg * mu * L2E, sw * rec_erev[idx], sw);
            }
            ((float4*)(ws + OFF_RP4))[q] = v;
        } else if (i < 64704) {
            int u = i - 64656;                 // u < 48
            float g = sp_(gleak[u]);
            ws[OFF_CM + u]       = sp_(cm[u]) * 6.f;
            ws[OFF_CM + 64 + u]  = g;
            ws[OFF_CM + 128 + u] = g * vleak[u];
        } else if (i < 89280) {                // w2b K-repacked frags (24576)
            int n = i - 64704;
            int j = n & 7, l = (n >> 3) & 63, t2 = n >> 9;   // t2 0..47
            int wv = t2 & 3;
            int r  = t2 >> 2;                  // 0..11 = (h*3+ky)*2+xp
            int xp = r & 1, hk = r >> 1;       // hk = h*3+ky
            int ky = hk % 3, h = hk / 3;
            int oc = wv * 16 + (l & 15);
            int kgB = l >> 4;
            int icl = (kgB & 1) * 8 + j;
            int ic = h * 16 + icl;
            int kx = 2 * xp + (kgB >> 1);
            float val = (kx == 3) ? 0.f : w2[((oc * 32 + ic) * 3 + ky) * 3 + kx];
            ((__hip_bfloat16*)(ws + OFF_W2B))[n] = __float2bfloat16(val);
        } else if (i < 107712) {               // w3b frags (unchanged mapping)
            int n = i - 89280;
            int j = n & 7, l = (n >> 3) & 63, t3 = n >> 9;
            int h = t3 & 1, u2 = t3 >> 1;
            int nt = u2 / 9, p = u2 % 9;
            int ky = p / 3, kx = p % 3;
            int oc = nt * 16 + (l & 15);
            int ic = h * 32 + (l >> 4) * 8 + j;
            ((__hip_bfloat16*)(ws + OFF_W3B))[n] =
                __float2bfloat16(w3[((oc * 64 + ic) * 3 + ky) * 3 + kx]);
        }
    } else {
        // ---- sensory compaction: block = u, deterministic ballot/scan ----
        float4* cp4 = (float4*)(ws + OFF_SP4);
        int* kix = (int*)(ws + OFF_SP4 + 98304);
        int* nnz = (int*)(ws + OFF_SP4 + 122880);
        const int u = blockIdx.x - 181;    // 0..47
        const int t = threadIdx.x;         // 0..255
        const int w = t >> 6, lane = t & 63;
        __shared__ int wcnt[4];
        __shared__ int basetot;
        if (t == 0) basetot = 0;
        __syncthreads();
#pragma unroll 1
        for (int c = 0; c < 6; ++c) {
            int k = c * 256 + t;
            bool m = (k < 1283) && (sens_mask[k * 48 + u] != 0);
            unsigned long long bal = __ballot(m);
            int prefix = __popcll(bal & ((1ULL << lane) - 1ULL));
            if (lane == 0) wcnt[w] = __popcll(bal);
            __syncthreads();                                   // wcnt visible
            int wbase = basetot;
            for (int ww = 0; ww < 4; ++ww) if (ww < w) wbase += wcnt[ww];
            if (m) {
                int pos = wbase + prefix;
                if (pos < SCAP) {
                    int idx = k * 48 + u;
                    float sw = sp_(sens_w[idx]);
                    float sg = sens_sigma[idx], mu = sens_mu[idx];
                    cp4[pos * 48 + u] = make_float4(-sg * L2E, sg * mu * L2E,
                                                    sw * sens_erev[idx], sw);
                    kix[pos * 48 + u] = k;
                }
            }
            __syncthreads();                                   // all used wcnt/basetot
            if (t == 0) basetot += wcnt[0] + wcnt[1] + wcnt[2] + wcnt[3];
            __syncthreads();                                   // basetot updated
        }
        int cnt = min(basetot, SCAP);
        for (int e = cnt + t; e < SCAP; e += 256) {            // zero-pad tail
            cp4[e * 48 + u] = make_float4(0.f, 0.f, 0.f, 0.f);
            kix[e * 48 + u] = 0;
        }
        if (t == 0) nnz[u] = cnt;
    }
}

// ---------------------------------------------------------------------------
// Fused CNN (verbatim from the 294.7us best).
// ---------------------------------------------------------------------------
#define IMGB 0
#define C1H  5424
#define A2E  0
#define A2O  12672
#define SMB  28272

__global__ __launch_bounds__(256, 4) void cnn_kernel(
    const float* __restrict__ depth, const float* __restrict__ relpos,
    const float* __restrict__ w1, const float* __restrict__ b1,
    const float* __restrict__ b2, const float* __restrict__ b3,
    const __hip_bfloat16* __restrict__ w2b, const __hip_bfloat16* __restrict__ w3b,
    float* __restrict__ seq) {
    __shared__ __align__(16) char smraw[SMB];
    const int t = threadIdx.x;
    const int img = blockIdx.x;
    const int l = t & 63;
    const int wvu = __builtin_amdgcn_readfirstlane(t >> 6);
    const int m = l & 15, kg = l >> 4;

    for (int i = t; i < 7068; i += 256) ((uint*)smraw)[i] = 0u;
    __syncthreads();
    for (int i = t; i < 1280; i += 256) {
        int pos = 2 * i;
        int h = pos >> 6, w = pos & 63;
        float2 d = *(const float2*)(depth + (long)img * 2560 + pos);
        __hip_bfloat162 pk = __float22bfloat162_rn(d);
        *(__hip_bfloat162*)(smraw + IMGB + ((h + 1) * 66 + (w + 2)) * 2) = pk;
    }
    __syncthreads();

    const __hip_bfloat16* imgp = (const __hip_bfloat16*)(smraw + IMGB);
    f32x4 acc[10];
    {
        float bias = b2[wvu * 16 + m];
#pragma unroll
        for (int mt = 0; mt < 10; ++mt) acc[mt] = (f32x4){bias, bias, bias, bias};
    }

#pragma unroll 1
    for (int h = 0; h < 2; ++h) {
        const int ocb = h * 16 + wvu * 4;      // uniform
        float wv4[4][9], bv4[4];
#pragma unroll
        for (int j = 0; j < 4; ++j) {
            bv4[j] = b1[ocb + j];
#pragma unroll
            for (int k = 0; k < 9; ++k) wv4[j][k] = w1[(ocb + j) * 9 + k];
        }
#pragma unroll 1
        for (int i = 0; i < 10; ++i) {
            int p = l + (i << 6);
            int y1 = p >> 5, x1 = p & 31;
            float xin[9];
#pragma unroll
            for (int ky = 0; ky < 3; ++ky)
#pragma unroll
                for (int kx = 0; kx < 3; ++kx)
                    xin[ky * 3 + kx] = __bfloat162float(imgp[(2 * y1 + ky) * 66 + 2 * x1 + kx + 1]);
            float o[4];
#pragma unroll
            for (int j = 0; j < 4; ++j) {
                float a = bv4[j];
#pragma unroll
                for (int k = 0; k < 9; ++k) a = fmaf(wv4[j][k], xin[k], a);
                o[j] = fmaxf(a, 0.f);
            }
            char* cb = smraw + C1H + (((y1 + 1) * 34) + (x1 + 1)) * 32 + wvu * 8;
            *(__hip_bfloat162*)cb       = __float22bfloat162_rn(make_float2(o[0], o[1]));
            *(__hip_bfloat162*)(cb + 4) = __float22bfloat162_rn(make_float2(o[2], o[3]));
        }
        bshort8 Bh[6];
#pragma unroll
        for (int f = 0; f < 6; ++f)
            Bh[f] = *(const bshort8*)(w2b + (((h * 6 + f) * 4 + wvu) * 64 + l) * 8);
        __syncthreads();   // c1h pass-h ready
#pragma unroll
        for (int ky = 0; ky < 3; ++ky) {
#pragma unroll
            for (int xp = 0; xp < 2; ++xp) {
                bshort8 Bp = Bh[ky * 2 + xp];
                const char* base = smraw + C1H + (ky * 34 + 2 * m + 2 * xp + (kg >> 1)) * 32 + (kg & 1) * 16;
#pragma unroll
                for (int mt = 0; mt < 10; ++mt) {
                    bshort8 A = *(const bshort8*)(base + mt * 2176);   // 2 rows * 34 cols * 32 B
                    acc[mt] = __builtin_amdgcn_mfma_f32_16x16x32_bf16(A, Bp, acc[mt], 0, 0, 0);
                }
            }
        }
        __syncthreads();   // reads done before next conv1 overwrite / a2 overlay
    }

    for (int i = t; i < 6336; i += 256) ((uint*)smraw)[i] = 0u;
    __syncthreads();
    {
        int oc = wvu * 16 + m;
        int q = oc >> 3, sub = oc & 7;
#pragma unroll
        for (int mt = 0; mt < 10; ++mt) {
            int row = mt + 1;
#pragma unroll
            for (int reg = 0; reg < 4; ++reg) {
                int x2 = kg * 4 + reg;
                int odd = x2 & 1;
                int xi = odd ? ((x2 + 1) >> 1) : (x2 >> 1);
                char* ab = smraw + (odd ? A2O : A2E);
                float v = fmaxf(acc[mt][reg], 0.f);
                *(__hip_bfloat16*)(ab + (((q * 11 + row) * 9 + xi) * 8 + sub) * 2) = __float2bfloat16(v);
            }
        }
    }
    __syncthreads();

    {
        const int nt = wvu & 1;
        const bool two = wvu < 2;
        f32x4 c3a = (f32x4){0.f, 0.f, 0.f, 0.f};
        f32x4 c3b = (f32x4){0.f, 0.f, 0.f, 0.f};
        const int xb = m & 7, yb = m >> 3;
#pragma unroll
        for (int p = 0; p < 9; ++p) {
            int ky = p / 3, kx = p % 3;
            const char* arr = smraw + ((kx == 1) ? A2E : A2O);
            int xi3 = xb + (kx == 2);
#pragma unroll
            for (int h = 0; h < 2; ++h) {
                bshort8 B = *(const bshort8*)(w3b + (((nt * 9 + p) * 2 + h) * 64 + l) * 8);
                int q = h * 4 + kg;
                const char* base = arr + ((q * 11 + 2 * yb + ky) * 9 + xi3) * 16;
                if (two) {
                    bshort8 A0 = *(const bshort8*)(base);
                    c3a = __builtin_amdgcn_mfma_f32_16x16x32_bf16(A0, B, c3a, 0, 0, 0);
                    bshort8 A2 = *(const bshort8*)(base + 1152);
                    c3b = __builtin_amdgcn_mfma_f32_16x16x32_bf16(A2, B, c3b, 0, 0, 0);
                } else {
                    bshort8 A1 = *(const bshort8*)(base + 576);
                    c3a = __builtin_amdgcn_mfma_f32_16x16x32_bf16(A1, B, c3a, 0, 0, 0);
                }
            }
        }
        __syncthreads();
        float* sb = (float*)smraw;
        int oc = nt * 16 + m;
        float bv = b3[oc];
        int ob40 = oc * 40;
        if (two) {
#pragma unroll
            for (int reg = 0; reg < 4; ++reg) {
                sb[ob40 + kg * 4 + reg] = fmaxf(c3a[reg] + bv, 0.f);
                int px2 = 32 + kg * 4 + reg;
                if (px2 < 40) sb[ob40 + px2] = fmaxf(c3b[reg] + bv, 0.f);
            }
        } else {
#pragma unroll
            for (int reg = 0; reg < 4; ++reg)
                sb[ob40 + 16 + kg * 4 + reg] = fmaxf(c3a[reg] + bv, 0.f);
        }
        __syncthreads();
        for (int i = t; i < 1283; i += 256)
            seq[(long)img * 1283 + i] = (i < 1280) ? sb[i] : relpos[img * 3 + (i - 1280)];
    }
}

// ---------------------------------------------------------------------------
// Sensory v2 SPARSE (verbatim from R10's 261.4us best).
// ---------------------------------------------------------------------------
__global__ __launch_bounds__(768) void sensory_kernel(
    const float* __restrict__ sp, const float* __restrict__ seq,
    const float* __restrict__ iw, const float* __restrict__ ibias,
    float2* __restrict__ part) {
    const float4* CP4 = (const float4*)sp;
    const int* KIX = (const int*)(sp + 98304);
    __shared__ __align__(16) char sbuf[49152];
    float*  IT  = (float*)sbuf;        // [8][1288] transposed I-table (41216 B)
    float2* red = (float2*)sbuf;       // reused after compute barrier
    const int t = threadIdx.x;
    const int pb = blockIdx.x * 8;

    for (int p = 0; p < 8; ++p)
        for (int k = t; k < 1283; k += 768)
            IT[p * 1288 + k] = fmaf(seq[(long)(pb + p) * 1283 + k], iw[k], ibias[k]);
    __syncthreads();

    const int u = t % 48, kg = t / 48;
    float2 acc[8];
#pragma unroll
    for (int p = 0; p < 8; ++p) acc[p] = make_float2(0.f, 0.f);

#pragma unroll 2
    for (int i = 0; i < 30; ++i) {
        int e = kg + 16 * i;                       // covers 0..479 exactly
        float4 pv = CP4[e * 48 + u];               // coalesced over u
        int k = KIX[e * 48 + u];
        const float* itk = IT + k;
        float r0 = __builtin_amdgcn_rcpf(1.f + __builtin_amdgcn_exp2f(fmaf(pv.x, itk[0 * 1288], pv.y)));
        float r1 = __builtin_amdgcn_rcpf(1.f + __builtin_amdgcn_exp2f(fmaf(pv.x, itk[1 * 1288], pv.y)));
        float r2 = __builtin_amdgcn_rcpf(1.f + __builtin_amdgcn_exp2f(fmaf(pv.x, itk[2 * 1288], pv.y)));
        float r3 = __builtin_amdgcn_rcpf(1.f + __builtin_amdgcn_exp2f(fmaf(pv.x, itk[3 * 1288], pv.y)));
        float r4 = __builtin_amdgcn_rcpf(1.f + __builtin_amdgcn_exp2f(fmaf(pv.x, itk[4 * 1288], pv.y)));
        float r5 = __builtin_amdgcn_rcpf(1.f + __builtin_amdgcn_exp2f(fmaf(pv.x, itk[5 * 1288], pv.y)));
        float r6 = __builtin_amdgcn_rcpf(1.f + __builtin_amdgcn_exp2f(fmaf(pv.x, itk[6 * 1288], pv.y)));
        float r7 = __builtin_amdgcn_rcpf(1.f + __builtin_amdgcn_exp2f(fmaf(pv.x, itk[7 * 1288], pv.y)));
        acc[0].x = fmaf(pv.z, r0, acc[0].x); acc[0].y = fmaf(pv.w, r0, acc[0].y);
        acc[1].x = fmaf(pv.z, r1, acc[1].x); acc[1].y = fmaf(pv.w, r1, acc[1].y);
        acc[2].x = fmaf(pv.z, r2, acc[2].x); acc[2].y = fmaf(pv.w, r2, acc[2].y);
        acc[3].x = fmaf(pv.z, r3, acc[3].x); acc[3].y = fmaf(pv.w, r3, acc[3].y);
        acc[4].x = fmaf(pv.z, r4, acc[4].x); acc[4].y = fmaf(pv.w, r4, acc[4].y);
        acc[5].x = fmaf(pv.z, r5, acc[5].x); acc[5].y = fmaf(pv.w, r5, acc[5].y);
        acc[6].x = fmaf(pv.z, r6, acc[6].x); acc[6].y = fmaf(pv.w, r6, acc[6].y);
        acc[7].x = fmaf(pv.z, r7, acc[7].x); acc[7].y = fmaf(pv.w, r7, acc[7].y);
    }
    __syncthreads();   // IT reads done; region reused as red
#pragma unroll
    for (int p = 0; p < 8; ++p) red[(kg * 8 + p) * 48 + u] = acc[p];
    __syncthreads();
    if (t < 384) {
        int p = t / 48, uu = t - p * 48;
        float sn = 0.f, sd = 0.f;
#pragma unroll
        for (int g = 0; g < 16; ++g) {
            float2 rr = red[(g * 8 + p) * 48 + uu];
            sn += rr.x; sd += rr.y;
        }
        part[(long)(pb + p) * 48 + uu] = make_float2(sn, sd);
    }
}

// ---------------------------------------------------------------------------
// Recurrent v9: v6 structure VERBATIM except the sigmoid inner loop is
// PAIRED: z0/d0 + z1/d1 = (z0*d1 + z1*d0) * rcp(d0*d1) -> 3 trans per pair
// (2 exp2 + 1 rcp) instead of 4. Trans issue 24->18 per unfold (-48cy of
// the ~730cy unfold critical path; at 1 wave/SIMD nothing hides trans
// issue). Exact in reals; d0*d1 <= 2^46 (no overflow); raw-rcp error
// unchanged in kind. Memory access pattern byte-identical to the proven
// 67.0us v6 (avoids the R1/R7 in-loop-load failure mode).
// Falsifier: recurrent unchanged at 67 -> critical path is barrier/LDS,
// not trans; stop touching recurrent math.
// ---------------------------------------------------------------------------
__global__ __launch_bounds__(192, 1) void recurrent_kernel(
    const float* __restrict__ rp, const float* __restrict__ cmglv,
    const float2* __restrict__ part,
    const float* __restrict__ out_w, const float* __restrict__ out_b,
    const float* __restrict__ head_w, const float* __restrict__ head_b,
    float* __restrict__ outp) {
    __shared__ float2 WL[1536];        // sensory partials for this batch
    __shared__ float  LV[2][64];       // v double-buffer
    __shared__ float  ym[4];
    const int t  = threadIdx.x;        // 0..191
    const int b  = blockIdx.x;
    const int u  = t >> 2;             // 0..47
    const int jq = t & 3;              // j-quarter

    // params in registers: j = jq*12 + r, dense [j][u64] float4 table
    const float4* RP4 = (const float4*)rp;
    float4 P[12];
#pragma unroll
    for (int r = 0; r < 12; ++r) P[r] = RP4[(jq * 12 + r) * 64 + u];
#pragma unroll
    for (int r = 0; r < 12; ++r) {
        asm volatile("" : "+v"(P[r].x), "+v"(P[r].y), "+v"(P[r].z), "+v"(P[r].w));
    }

    // stage sensory partials for this batch
    for (int i = t; i < 1536; i += 192) WL[i] = part[(long)b * 1536 + i];
    if (t < 64) { LV[0][t] = 0.f; LV[1][t] = 0.f; }

    const float cmt = cmglv[u], gl = cmglv[64 + u], glv = cmglv[128 + u];
    const float cg  = cmt + gl + 1e-8f;
    float ow = 0.f, ob = 0.f;
    const bool lead = (jq == 0) && (u < 4);
    if (lead) { ow = out_w[u]; ob = out_b[u]; }
    __syncthreads();

    float vn = 0.f, yacc = 0.f;
    int buf = 0;
#pragma unroll 1
    for (int s = 0; s < 32; ++s) {
        float2 wnd = WL[s * 48 + u];
        const float basen = glv + wnd.x;       // per-step invariants
        const float based = cg + wnd.y;
#pragma unroll
        for (int unf = 0; unf < 6; ++unf) {
            const float4* lv4 = (const float4*)&LV[buf][jq * 12];
            float4 V0 = lv4[0], V1 = lv4[1], V2 = lv4[2];
            float va[12] = {V0.x, V0.y, V0.z, V0.w, V1.x, V1.y, V1.z, V1.w,
                            V2.x, V2.y, V2.z, V2.w};
            float pn = 0.f, pd = 0.f;
#pragma unroll
            for (int q = 0; q < 6; ++q) {
                const int r0 = 2 * q, r1 = 2 * q + 1;
                float e0 = __builtin_amdgcn_exp2f(fmaf(P[r0].x, va[r0], P[r0].y));
                float e1 = __builtin_amdgcn_exp2f(fmaf(P[r1].x, va[r1], P[r1].y));
                float d0 = 1.f + e0, d1 = 1.f + e1;
                float sc = __builtin_amdgcn_rcpf(d0 * d1);
                float tn = fmaf(P[r0].z, d1, P[r1].z * d0);
                float td = fmaf(P[r0].w, d1, P[r1].w * d0);
                pn = fmaf(tn, sc, pn);
                pd = fmaf(td, sc, pd);
            }
            // quad reduce over the 4 j-quarters: DPP quad_perm, all-VALU
            pn += qxor1_(pn); pd += qxor1_(pd);
            pn += qxor2_(pn); pd += qxor2_(pd);
            float num = fmaf(cmt, vn, basen) + pn;
            float den = based + pd;
            float r0 = __builtin_amdgcn_rcpf(den);
            r0 = r0 * fmaf(-den, r0, 2.f);       // 1 Newton step: ~1 ulp
            vn = num * r0;
            if (jq == 0) LV[buf ^ 1][u] = vn;
            __syncthreads();
            buf ^= 1;
        }
        if (lead) yacc = fmaf(vn, ow, yacc) + ob;
    }
    if (lead) ym[u] = yacc;
    __syncthreads();
    if (t < 2) {
        const float inv = 1.f / 32.f;
        float o = fmaf(ym[0] * inv, head_w[t],
                  fmaf(ym[1] * inv, head_w[2 + t],
                  fmaf(ym[2] * inv, head_w[4 + t],
                  fmaf(ym[3] * inv, head_w[6 + t], head_b[t]))));
        outp[b * 2 + t] = tanhf(o);
    }
}

extern "C" void kernel_launch(void* const* d_in, const int* in_sizes, int n_in,
                              void* d_out, int out_size, void* d_ws, size_t ws_size,
                              hipStream_t stream) {
    const float* depth      = (const float*)d_in[0];
    const float* relpos     = (const float*)d_in[1];
    const float* w1         = (const float*)d_in[2];
    const float* b1         = (const float*)d_in[3];
    const float* w2         = (const float*)d_in[4];
    const float* b2         = (const float*)d_in[5];
    const float* w3         = (const float*)d_in[6];
    const float* b3         = (const float*)d_in[7];
    const float* iw         = (const float*)d_in[8];
    const float* ibias      = (const float*)d_in[9];
    const float* sens_w     = (const float*)d_in[10];
    const float* sens_mu    = (const float*)d_in[11];
    const float* sens_sigma = (const float*)d_in[12];
    const float* sens_erev  = (const float*)d_in[13];
    const float* rec_w      = (const float*)d_in[14];
    const float* rec_mu     = (const float*)d_in[15];
    const float* rec_sigma  = (const float*)d_in[16];
    const float* rec_erev   = (const float*)d_in[17];
    const float* gleak      = (const float*)d_in[18];
    const float* vleak      = (const float*)d_in[19];
    const float* cm         = (const float*)d_in[20];
    const float* out_w      = (const float*)d_in[21];
    const float* out_b      = (const float*)d_in[22];
    const float* head_w     = (const float*)d_in[23];
    const float* head_b     = (const float*)d_in[24];
    const int*   sens_mask  = (const int*)d_in[25];
    const int*   rec_mask   = (const int*)d_in[26];

    float* ws  = (float*)d_ws;
    float* out = (float*)d_out;

    prep_kernel<<<229, 256, 0, stream>>>(rec_w, rec_mu, rec_sigma, rec_erev, rec_mask,
                                         gleak, vleak, cm, w2, w3,
                                         sens_w, sens_mu, sens_sigma, sens_erev, sens_mask,
                                         ws);
    cnn_kernel<<<2048, 256, 0, stream>>>(depth, relpos, w1, b1, b2, b3,
                                         (const __hip_bfloat16*)(ws + OFF_W2B),
                                         (const __hip_bfloat16*)(ws + OFF_W3B),
                                         ws + OFF_SEQ);
    sensory_kernel<<<256, 768, 0, stream>>>(ws + OFF_SP4, ws + OFF_SEQ, iw, ibias,
                                            (float2*)(ws + OFF_PART));
    recurrent_kernel<<<64, 192, 0, stream>>>(ws + OFF_RP4, ws + OFF_CM,
                                             (const float2*)(ws + OFF_PART),
                                             out_w, out_b, head_w, head_b, out);
}